// Round 4
// baseline (510.114 us; speedup 1.0000x reference)
//
#include <hip/hip_runtime.h>
#include <hip/hip_bf16.h>
#include <math.h>

typedef __hip_bfloat16 bf16;
typedef __attribute__((ext_vector_type(4))) float f32x4;
typedef __attribute__((ext_vector_type(8))) short short8;

#define HIDN 768
#define NTOK 2048   // B*S
#define NH 12
#define HD 64
#define ISZ 3072
#define SEQ 512

__device__ __forceinline__ bf16 f2bf(float x){ return __float2bfloat16(x); }
__device__ __forceinline__ float gelu_f(float x){ return 0.5f*x*(1.0f + erff(x*0.70710678118654752f)); }

// async global->LDS, 16B per lane (LDS dest = wave base + lane*16)
__device__ __forceinline__ void gload16(const bf16* g, bf16* l){
    __builtin_amdgcn_global_load_lds(
        (const __attribute__((address_space(1))) unsigned int*)g,
        (__attribute__((address_space(3))) unsigned int*)l,
        16, 0, 0);
}

// ---------------------------------------------------------------------------
// 8-phase 256x256 GEMM (m201 template, plain HIP): C = A[M,K] @ B[N,K]^T.
// BM=BN=256, BK=64, 512 threads = 8 waves (2M x 4N), per-wave out 128x64.
// LDS 128KB: A 2buf x 256rows x 128B, B same. Full 3-bit XOR granule swizzle
// (pre-swizzled global source, swizzled ds_read). Per K-tile: 4 quadrant
// phases, each {ds_read subtile | stage 1 half-tile | barrier | 16 MFMA
// (setprio) | barrier}; ONE counted s_waitcnt vmcnt(4) per K-tile (at P3),
// vmcnt(0) only at the drain tile. Staging ledger:
//   P0/P1 stage B-halves of tile T+1 (other buf; its last read was P2 of T-1)
//   P2/P3 stage A-halves of tile T+2 (cur buf; rows last read at P1 of T)
// Reads complete before phase-end barrier (data-dep lgkm waits before MFMA),
// so overwrites issued in a later phase are safe. z-batched via strides.
// EPI: 2 = gelu(v+bias), bf16      (FFN1)
//      3 = atomicAdd(C[(row&2047)*ldc+col], v*scales[sb+(row>>11)]) (FFN2)
// Requires M%256==0, N%256==0, K%64==0, K/64 >= 2.
// ---------------------------------------------------------------------------
#define BARR do{ asm volatile("" ::: "memory"); __builtin_amdgcn_s_barrier(); asm volatile("" ::: "memory"); }while(0)

template<int EPI>
__global__ __launch_bounds__(512, 2)
void gemm8p(const bf16* __restrict__ Abase, const bf16* __restrict__ Bbase,
            void* __restrict__ Cbase, const float* __restrict__ bias,
            const float* __restrict__ scales, int scale_base,
            int K, int lda, int ldb, int ldc,
            long sAz, long sBz, long sCz)
{
    __shared__ __align__(16) char lds[131072];  // A: [2][256][128B] @0; B: @65536

    int bz = blockIdx.z;
    const bf16* A = Abase + (long)bz*sAz;
    const bf16* B = Bbase + (long)bz*sBz;

    // XCD-bijective swizzle over the x-y plane
    int nwg  = gridDim.x * gridDim.y;
    int orig = blockIdx.y * gridDim.x + blockIdx.x;
    int q8 = nwg >> 3, r8 = nwg & 7;
    int xcd = orig & 7, idx = orig >> 3;
    int wg = (xcd < r8 ? xcd*(q8+1) : r8*(q8+1) + (xcd-r8)*q8) + idx;
    int bn = wg % gridDim.x, bm = wg / gridDim.x;

    int t = threadIdx.x;
    int lane = t & 63, wave = t >> 6;
    int wm = (wave >> 2) << 7;     // 0 / 128
    int wn = (wave & 3) << 6;      // 0 / 64 / 128 / 192
    int lr = lane & 15, lg = lane >> 4;
    int x7 = lr & 7;
    int pk0 = ((lg      ^ x7) << 4);   // phys granule byte off, kstep 0
    int pk1 = (((4|lg)  ^ x7) << 4);   // kstep 1

    // staging: thread t -> row (t>>3) of a 64-row chunk, pre-swizzled granule
    int srow = t >> 3;
    int glog = (t & 7) ^ (srow & 7);
    const bf16* Asrc = A + (long)(bm*256 + srow)*lda + glog*8;
    const bf16* Bsrc = B + (long)(bn*256 + srow)*ldb + glog*8;
    int dst16 = t * 16;

#define STAGE_A(buf, half, kt) do { \
    char* p = lds + (buf)*32768 + (half)*16384 + dst16; \
    const bf16* s = Asrc + (long)((half)*128)*lda + (long)(kt)*64; \
    gload16(s, (bf16*)p); \
    gload16(s + (long)64*lda, (bf16*)(p + 8192)); } while(0)

#define STAGE_B(buf, half, kt) do { \
    char* p = lds + 65536 + (buf)*32768 + (half)*16384 + dst16; \
    const bf16* s = Bsrc + (long)((half)*128)*ldb + (long)(kt)*64; \
    gload16(s, (bf16*)p); \
    gload16(s + (long)64*ldb, (bf16*)(p + 8192)); } while(0)

#define LDA_HALF(arr, buf, mh) do { \
    const char* pb = lds + (buf)*32768 + (wm+lr)*128 + (mh)*8192; \
    _Pragma("unroll") for (int m=0;m<4;m++){ \
        arr[m*2+0] = *(const short8*)(pb + m*2048 + pk0); \
        arr[m*2+1] = *(const short8*)(pb + m*2048 + pk1); } } while(0)

#define LDB_PAIR(arr, buf, nh) do { \
    const char* pb = lds + 65536 + (buf)*32768 + (wn+lr)*128 + (nh)*4096; \
    _Pragma("unroll") for (int n=0;n<2;n++){ \
        arr[n*2+0] = *(const short8*)(pb + n*2048 + pk0); \
        arr[n*2+1] = *(const short8*)(pb + n*2048 + pk1); } } while(0)

#define MM(mh, nh, aa, bb) do { \
    __builtin_amdgcn_s_setprio(1); \
    _Pragma("unroll") for (int m=0;m<4;m++) \
    _Pragma("unroll") for (int n=0;n<2;n++) \
    _Pragma("unroll") for (int k=0;k<2;k++) \
        acc[(mh)*4+m][(nh)*2+n] = __builtin_amdgcn_mfma_f32_16x16x32_bf16( \
            aa[m*2+k], bb[n*2+k], acc[(mh)*4+m][(nh)*2+n], 0,0,0); \
    __builtin_amdgcn_s_setprio(0); } while(0)

    f32x4 acc[8][4] = {};
    short8 a0[8], a1[8], b0[4], b1[4];

    // prologue: tile0 full + tile1 A-halves; retire tile0, keep 2 half-tiles in flight
    STAGE_A(0,0,0); STAGE_A(0,1,0);
    STAGE_B(0,0,0); STAGE_B(0,1,0);
    STAGE_A(1,0,1); STAGE_A(1,1,1);
    asm volatile("s_waitcnt vmcnt(4)" ::: "memory");
    BARR;

    int NT = K >> 6;
    int cur = 0;
    for (int T = 0; T < NT; ++T){
        int doB = (T < NT-1);
        int doA = (T < NT-2);
        // P0: quadrant (m-half0, n-half0)
        LDA_HALF(a0, cur, 0); LDB_PAIR(b0, cur, 0);
        if (doB) STAGE_B(cur^1, 0, T+1);
        BARR; MM(0,0,a0,b0); BARR;
        // P1: (m-half1, n-half0)
        LDA_HALF(a1, cur, 1);
        if (doB) STAGE_B(cur^1, 1, T+1);
        BARR; MM(1,0,a1,b0); BARR;
        // P2: (m-half0, n-half1)
        LDB_PAIR(b1, cur, 1);
        if (doA) STAGE_A(cur, 0, T+2);
        BARR; MM(0,1,a0,b1); BARR;
        // P3: (m-half1, n-half1) + the ONE per-tile vmcnt gate
        if (doA) STAGE_A(cur, 1, T+2);
        BARR; MM(1,1,a1,b1);
        if (T < NT-2)       asm volatile("s_waitcnt vmcnt(4)" ::: "memory");
        else if (T == NT-2) asm volatile("s_waitcnt vmcnt(0)" ::: "memory");
        BARR;
        cur ^= 1;
    }

#undef STAGE_A
#undef STAGE_B
#undef LDA_HALF
#undef LDB_PAIR
#undef MM

    // epilogue: C/D layout col=lane&15, row=(lane>>4)*4+i
    #pragma unroll
    for (int am=0; am<8; am++){
        #pragma unroll
        for (int an=0; an<4; an++){
            int col = bn*256 + wn + (an>>1)*32 + (an&1)*16 + lr;
            float bcol = (EPI==2) ? bias[col] : 0.f;
            #pragma unroll
            for (int i=0;i<4;i++){
                long row = (long)bm*256 + wm + (am>>2)*64 + (am&3)*16 + lg*4 + i;
                float v = acc[am][an][i];
                if constexpr (EPI==2){
                    ((bf16*)Cbase + (long)bz*sCz)[row*ldc+col] = f2bf(gelu_f(v + bcol));
                } else {
                    unsafeAtomicAdd((float*)Cbase + (row & (NTOK-1))*ldc + col,
                                    v * scales[scale_base + (int)(row>>11)]);
                }
            }
        }
    }
}

// ---------------------------------------------------------------------------
// Generic bf16 GEMM (m97 structure) for the smaller/odd-shaped matmuls.
// EPI: 0 = bias, bf16 out              (QKV)
//      1 = scale[zq]*(v+bias), bf16    (per-head Wo, scale=w_kp)
//      4 = v*0.125 + bias[col], f32    (attention scores + mask)
//      5 = bf16 out, col<Nvalid guard  (PV)
// ---------------------------------------------------------------------------
template<int EPI>
__global__ __launch_bounds__(256)
void gemm_bt(const bf16* __restrict__ Abase, const bf16* __restrict__ Bbase,
             void* __restrict__ Cbase, const float* __restrict__ biasBase,
             const float* __restrict__ scales,
             int K, int lda, int ldb, int ldc, int Nvalid,
             int zb0, int zdiv, int scale_base,
             long sAq, long sAr, long sAz,
             long sBq, long sBr, long sBz,
             long sCq, long sCr, long sCz,
             long sBiasq)
{
    int bz = blockIdx.z;
    int za = zb0 + bz;
    int zq = za / zdiv, zr = za - zq*zdiv;
    const bf16* A = Abase + (long)zq*sAq + (long)zr*sAr + (long)bz*sAz;
    const bf16* B = Bbase + (long)zq*sBq + (long)zr*sBr + (long)bz*sBz;
    const float* bias = biasBase ? (biasBase + (long)zq*sBiasq) : nullptr;
    long coff = (long)zq*sCq + (long)zr*sCr + (long)bz*sCz;

    __shared__ bf16 As[128*32];
    __shared__ bf16 Bs[128*32];

    int nwg  = gridDim.x * gridDim.y;
    int orig = blockIdx.y * gridDim.x + blockIdx.x;
    int q8 = nwg >> 3, r8 = nwg & 7;
    int xcd = orig & 7, idx = orig >> 3;
    int wg = (xcd < r8 ? xcd*(q8+1) : r8*(q8+1) + (xcd-r8)*q8) + idx;
    int bn = wg % gridDim.x, bm = wg / gridDim.x;

    int t = threadIdx.x;
    int wave = t >> 6, lane = t & 63;
    int wm = (wave >> 1) << 6;   // 0 or 64
    int wn = (wave & 1) << 6;
    int lr = lane & 15, lg = lane >> 4;

    f32x4 acc[4][4] = {};

    int arow = t >> 2;              // 0..63
    int acol = (t & 3) << 3;        // 0,8,16,24
    const bf16* Ag0 = A + (long)(bm*128 + arow)*lda + acol;
    const bf16* Ag1 = Ag0 + (long)64*lda;
    const bf16* Bg0 = B + (long)(bn*128 + arow)*ldb + acol;
    const bf16* Bg1 = Bg0 + (long)64*ldb;
    bf16* Al = As + t*8;
    bf16* Bl = Bs + t*8;

    for (int k0 = 0; k0 < K; k0 += 32) {
        __syncthreads();
        gload16(Ag0, Al);
        gload16(Ag1, Al + 64*32);
        gload16(Bg0, Bl);
        gload16(Bg1, Bl + 64*32);
        Ag0 += 32; Ag1 += 32; Bg0 += 32; Bg1 += 32;
        __syncthreads();
        short8 af[4], bfr[4];
        #pragma unroll
        for (int m=0;m<4;m++) af[m]  = *(short8*)&As[(wm + m*16 + lr)*32 + lg*8];
        #pragma unroll
        for (int n=0;n<4;n++) bfr[n] = *(short8*)&Bs[(wn + n*16 + lr)*32 + lg*8];
        #pragma unroll
        for (int m=0;m<4;m++)
            #pragma unroll
            for (int n=0;n<4;n++)
                acc[m][n] = __builtin_amdgcn_mfma_f32_16x16x32_bf16(af[m], bfr[n], acc[m][n], 0,0,0);
    }

    #pragma unroll
    for (int m=0;m<4;m++){
        #pragma unroll
        for (int n=0;n<4;n++){
            int col = bn*128 + wn + n*16 + lr;
            float bcol = 0.f;
            if constexpr (EPI==0||EPI==1||EPI==4) bcol = bias[col];
            #pragma unroll
            for (int i=0;i<4;i++){
                long row = (long)bm*128 + wm + m*16 + lg*4 + i;
                float v = acc[m][n][i];
                if constexpr (EPI==0){
                    ((bf16*)Cbase + coff)[row*ldc+col] = f2bf(v + bcol);
                } else if constexpr (EPI==1){
                    ((bf16*)Cbase + coff)[row*ldc+col] = f2bf(scales[zq]*(v + bcol));
                } else if constexpr (EPI==4){
                    ((float*)Cbase + coff)[row*ldc+col] = v*0.125f + bcol;
                } else {
                    if (col < Nvalid) ((bf16*)Cbase + coff)[row*ldc+col] = f2bf(v);
                }
            }
        }
    }
}

// ---------------------------------------------------------------------------
__global__ __launch_bounds__(256)
void transpose_cvt(const float* __restrict__ src, bf16* __restrict__ dst,
                   int R, int C, long sSrcZ, long sDstZ)
{
    __shared__ float tile[32][33];
    src += (long)blockIdx.z * sSrcZ;
    dst += (long)blockIdx.z * sDstZ;
    int c0 = blockIdx.x*32, r0 = blockIdx.y*32;
    int tx = threadIdx.x & 31, ty = threadIdx.x >> 5;
    #pragma unroll
    for (int i=0;i<32;i+=8) tile[ty+i][tx] = src[(long)(r0+ty+i)*C + c0+tx];
    __syncthreads();
    #pragma unroll
    for (int i=0;i<32;i+=8) dst[(long)(c0+ty+i)*R + r0+tx] = f2bf(tile[tx][ty+i]);
}

__global__ __launch_bounds__(256)
void transpose_v(const bf16* __restrict__ qkv, bf16* __restrict__ Vt, int zb0)
{
    __shared__ bf16 tile[32][33];
    int za = zb0 + blockIdx.z; int b = za/NH, h = za - b*NH;
    const bf16* src = qkv + (long)b*SEQ*3*HIDN + 2*HIDN + h*HD;
    bf16* dst = Vt + (long)blockIdx.z*128*SEQ;
    int d0 = blockIdx.x*32, s0 = blockIdx.y*32;
    int tx = threadIdx.x & 31, ty = threadIdx.x >> 5;
    #pragma unroll
    for (int i=0;i<32;i+=8) tile[ty+i][tx] = src[(long)(s0+ty+i)*(3*HIDN) + d0+tx];
    __syncthreads();
    #pragma unroll
    for (int i=0;i<32;i+=8) dst[(long)(d0+ty+i)*SEQ + s0+tx] = tile[tx][ty+i];
}

__global__ void cvt_bf16(const float* __restrict__ in, bf16* __restrict__ out, int n){
    int i = blockIdx.x*blockDim.x + threadIdx.x;
    if (i < n) out[i] = f2bf(in[i]);
}

__global__ void concat_bias(const float* __restrict__ bq, const float* __restrict__ bk,
                            const float* __restrict__ bv, float* __restrict__ bqkv){
    int i = blockIdx.x*blockDim.x + threadIdx.x;
    if (i < 3*HIDN) bqkv[i] = (i < HIDN) ? bq[i] : (i < 2*HIDN ? bk[i-HIDN] : bv[i-2*HIDN]);
}

__global__ __launch_bounds__(256)
void softmax_rows(const float* __restrict__ scores, bf16* __restrict__ probs)
{
    __shared__ float red[8];
    long row = blockIdx.x;
    const float* s = scores + row*SEQ;
    bf16* p = probs + row*SEQ;
    int t = threadIdx.x;
    int wave = t>>6, lane = t&63;
    float a = s[t], b2 = s[t+256];
    float m = fmaxf(a,b2);
    #pragma unroll
    for (int o=32;o>0;o>>=1) m = fmaxf(m, __shfl_xor(m,o,64));
    if (lane==0) red[wave]=m;
    __syncthreads();
    m = fmaxf(fmaxf(red[0],red[1]),fmaxf(red[2],red[3]));
    float e0 = __expf(a-m), e1 = __expf(b2-m);
    float sum = e0+e1;
    #pragma unroll
    for (int o=32;o>0;o>>=1) sum += __shfl_xor(sum,o,64);
    __syncthreads();
    if (lane==0) red[4+wave]=sum;
    __syncthreads();
    sum = red[4]+red[5]+red[6]+red[7];
    float inv = 1.0f/sum;
    p[t]     = f2bf(e0*inv);
    p[t+256] = f2bf(e1*inv);
}

__global__ __launch_bounds__(256)
void add_ln(const float* __restrict__ hidden, const float* __restrict__ out_acc,
            const float* __restrict__ bout, const float* __restrict__ w_a,
            const float* __restrict__ gamma, const float* __restrict__ beta,
            float* __restrict__ out)
{
    __shared__ float red[8];
    int row = blockIdx.x;
    int t = threadIdx.x;
    int wave = t>>6, lane = t&63;
    float swa = 0.f;
    #pragma unroll
    for (int h=0;h<NH;h++) swa += w_a[h];
    float x[3];
    float sum = 0.f;
    #pragma unroll
    for (int j=0;j<3;j++){
        int c = j*256 + t;
        x[j] = hidden[(long)row*HIDN + c] + out_acc[(long)row*HIDN + c] + swa*bout[c];
        sum += x[j];
    }
    #pragma unroll
    for (int o=32;o>0;o>>=1) sum += __shfl_xor(sum,o,64);
    if (lane==0) red[wave]=sum;
    __syncthreads();
    sum = red[0]+red[1]+red[2]+red[3];
    float u = sum * (1.0f/768.0f);
    float vs = 0.f;
    #pragma unroll
    for (int j=0;j<3;j++){ float d = x[j]-u; vs += d*d; }
    #pragma unroll
    for (int o=32;o>0;o>>=1) vs += __shfl_xor(vs,o,64);
    __syncthreads();
    if (lane==0) red[4+wave]=vs;
    __syncthreads();
    vs = red[4]+red[5]+red[6]+red[7];
    float rstd = rsqrtf(vs*(1.0f/768.0f) + 1e-12f);
    #pragma unroll
    for (int j=0;j<3;j++){
        int c = j*256 + t;
        out[(long)row*HIDN + c] = gamma[c]*(x[j]-u)*rstd + beta[c];
    }
}

extern "C" void kernel_launch(void* const* d_in, const int* in_sizes, int n_in,
                              void* d_out, int out_size, void* d_ws, size_t ws_size,
                              hipStream_t stream)
{
    const float* hidden = (const float*)d_in[0];
    const float* mask   = (const float*)d_in[1];
    const float* Wq = (const float*)d_in[2];
    const float* bq = (const float*)d_in[3];
    const float* Wk = (const float*)d_in[4];
    const float* bk = (const float*)d_in[5];
    const float* Wv = (const float*)d_in[6];
    const float* bv = (const float*)d_in[7];
    const float* Wo = (const float*)d_in[8];
    const float* bo = (const float*)d_in[9];
    const float* w_kp = (const float*)d_in[10];
    const float* w_a  = (const float*)d_in[11];
    const float* Wi = (const float*)d_in[12];
    const float* bi = (const float*)d_in[13];
    const float* Wout = (const float*)d_in[14];
    const float* boutp = (const float*)d_in[15];
    const float* gamma = (const float*)d_in[16];
    const float* beta  = (const float*)d_in[17];
    float* out = (float*)d_out;

    char* w = (char*)d_ws;
    auto alloc = [&](size_t bytes)->char* {
        char* p = w; w += (bytes + 255) & ~(size_t)255; return p;
    };
    bf16*  hbf    = (bf16*) alloc((size_t)NTOK*HIDN*2);
    bf16*  WqkvT  = (bf16*) alloc((size_t)3*HIDN*HIDN*2);
    float* bqkv   = (float*)alloc((size_t)3*HIDN*4);
    bf16*  WoT    = (bf16*) alloc((size_t)NH*HIDN*HD*2);
    bf16*  WiT    = (bf16*) alloc((size_t)ISZ*HIDN*2);
    bf16*  WoutT  = (bf16*) alloc((size_t)HIDN*ISZ*2);
    bf16*  qkv    = (bf16*) alloc((size_t)NTOK*3*HIDN*2);
    bf16*  ctx    = (bf16*) alloc((size_t)NH*NTOK*HD*2);
    float* out_acc= (float*)alloc((size_t)NTOK*HIDN*4);
    size_t fixed = (size_t)(w - (char*)d_ws);
    size_t avail = ws_size > fixed ? ws_size - fixed : 0;

    const size_t perZ = (size_t)SEQ*SEQ*4 + (size_t)SEQ*SEQ*2 + (size_t)128*SEQ*2;
    int ZB = 48;
    while (ZB > 6 && perZ*(size_t)ZB > avail) ZB >>= 1;
    const size_t perH = (size_t)NTOK*HIDN*2 + (size_t)NTOK*ISZ*2;
    static const int hcs[6] = {12,6,4,3,2,1};
    int HC = 1;
    for (int i=0;i<6;i++){ if (perH*(size_t)hcs[i] <= avail){ HC = hcs[i]; break; } }

    char* big = w;
    float* scores = (float*)big;
    bf16*  probs  = (bf16*)(big + (size_t)ZB*SEQ*SEQ*4);
    bf16*  Vt     = (bf16*)(big + (size_t)ZB*SEQ*SEQ*4 + (size_t)ZB*SEQ*SEQ*2);
    bf16*  xbuf   = (bf16*)big;
    bf16*  inter  = (bf16*)(big + (size_t)HC*NTOK*HIDN*2);

    // ---- prep ----
    cvt_bf16<<<(NTOK*HIDN+255)/256, 256, 0, stream>>>(hidden, hbf, NTOK*HIDN);
    concat_bias<<<(3*HIDN+255)/256, 256, 0, stream>>>(bq, bk, bv, bqkv);
    transpose_cvt<<<dim3(HIDN/32, HIDN/32, 1), 256, 0, stream>>>(Wq, WqkvT,              HIDN, HIDN, 0, 0);
    transpose_cvt<<<dim3(HIDN/32, HIDN/32, 1), 256, 0, stream>>>(Wk, WqkvT + HIDN*HIDN,  HIDN, HIDN, 0, 0);
    transpose_cvt<<<dim3(HIDN/32, HIDN/32, 1), 256, 0, stream>>>(Wv, WqkvT + 2*HIDN*HIDN,HIDN, HIDN, 0, 0);
    transpose_cvt<<<dim3(ISZ/32,  HIDN/32, 1), 256, 0, stream>>>(Wi,   WiT,   HIDN, ISZ, 0, 0);
    transpose_cvt<<<dim3(HIDN/32, ISZ/32,  1), 256, 0, stream>>>(Wout, WoutT, ISZ, HIDN, 0, 0);
    transpose_cvt<<<dim3(HIDN/32, HD/32,  NH), 256, 0, stream>>>(Wo,   WoT,   HD, HIDN,
                                                                 (long)HD*HIDN, (long)HIDN*HD);

    // ---- QKV projection ----
    gemm_bt<0><<<dim3(3*HIDN/128, NTOK/128, 1), 256, 0, stream>>>(
        hbf, WqkvT, qkv, bqkv, nullptr,
        HIDN, HIDN, HIDN, 3*HIDN, 3*HIDN,
        0, 1, 0,
        0,0,0, 0,0,0, 0,0,0, 0);

    // ---- attention ----
    hipMemsetAsync(Vt, 0, (size_t)ZB*128*SEQ*2, stream);
    for (int g = 0; g < 48; g += ZB) {
        transpose_v<<<dim3(2,16,ZB), 256, 0, stream>>>(qkv, Vt, g);
        gemm_bt<4><<<dim3(SEQ/128, SEQ/128, ZB), 256, 0, stream>>>(
            qkv, qkv + HIDN, scores, mask, nullptr,
            HD, 3*HIDN, 3*HIDN, SEQ, SEQ,
            g, NH, 0,
            (long)SEQ*3*HIDN, HD, 0,
            (long)SEQ*3*HIDN, HD, 0,
            0, 0, (long)SEQ*SEQ,
            SEQ);
        softmax_rows<<<ZB*SEQ, 256, 0, stream>>>(scores, probs);
        gemm_bt<5><<<dim3(1, SEQ/128, ZB), 256, 0, stream>>>(
            probs, Vt, ctx, nullptr, nullptr,
            SEQ, SEQ, SEQ, HD, HD,
            g, NH, 0,
            0, 0, (long)SEQ*SEQ,
            0, 0, (long)128*SEQ,
            (long)SEQ*HD, (long)NTOK*HD, 0,
            0);
    }

    // ---- per-head Wo -> FFN (8-phase 256^2 GEMMs) ----
    hipMemsetAsync(out_acc, 0, (size_t)NTOK*HIDN*4, stream);
    for (int c = 0; c < NH; c += HC) {
        gemm_bt<1><<<dim3(HIDN/128, NTOK/128, HC), 256, 0, stream>>>(
            ctx, WoT, xbuf, bo, w_kp,
            HD, HD, HD, HIDN, HIDN,
            c, 1, 0,
            (long)NTOK*HD, 0, 0,
            (long)HIDN*HD, 0, 0,
            0, 0, (long)NTOK*HIDN,
            HIDN);
        // inter[h] = gelu(x_h @ Wi^T + bi)   z-batched: M=2048, N=3072, K=768
        gemm8p<2><<<dim3(ISZ/256, NTOK/256, HC), 512, 0, stream>>>(
            xbuf, WiT, inter, bi, nullptr, 0,
            HIDN, HIDN, HIDN, ISZ,
            (long)NTOK*HIDN, 0, (long)NTOK*ISZ);
        // out_acc[token] += w_a[h]*(inter @ Wout^T)  split-K=2: M=HC*2048, N=768
        gemm8p<3><<<dim3(HIDN/256, HC*NTOK/256, 2), 512, 0, stream>>>(
            inter, WoutT, out_acc, nullptr, w_a, c,
            ISZ/2, ISZ, ISZ, HIDN,
            (long)(ISZ/2), (long)(ISZ/2), 0);
    }

    // ---- residual + sum(w_a)*bout + LayerNorm ----
    add_ln<<<NTOK, 256, 0, stream>>>(hidden, out_acc, boutp, w_a, gamma, beta, out);
}

// Round 5
// 321.636 us; speedup vs baseline: 1.5860x; 1.5860x over previous
//
#include <hip/hip_runtime.h>
#include <hip/hip_bf16.h>
#include <math.h>

typedef __hip_bfloat16 bf16;
typedef __attribute__((ext_vector_type(4))) float f32x4;
typedef __attribute__((ext_vector_type(8))) short short8;

#define HIDN 768
#define NTOK 2048   // B*S
#define NH 12
#define HD 64
#define ISZ 3072
#define SEQ 512

__device__ __forceinline__ bf16 f2bf(float x){ return __float2bfloat16(x); }
__device__ __forceinline__ float gelu_f(float x){ return 0.5f*x*(1.0f + erff(x*0.70710678118654752f)); }

// async global->LDS, 16B per lane (LDS dest = wave base + lane*16)
__device__ __forceinline__ void gload16(const bf16* g, bf16* l){
    __builtin_amdgcn_global_load_lds(
        (const __attribute__((address_space(1))) unsigned int*)g,
        (__attribute__((address_space(3))) unsigned int*)l,
        16, 0, 0);
}

// ---------------------------------------------------------------------------
// Generic bf16 GEMM (m97 structure): C = A[M,K] @ B[N,K]^T, both K-major.
// 128x128 tile, BK=32, 256 threads = 4 waves. global_load_lds staging.
// EPI: 0 = bias, bf16 out              (QKV)
//      4 = v*0.125 + bias[col], f32    (attention scores + mask)
//      5 = bf16 out, col<Nvalid guard  (PV, WcT)
//      6 = unsafeAtomicAdd f32, no scale (FFN2' split-K)
// ---------------------------------------------------------------------------
template<int EPI>
__global__ __launch_bounds__(256)
void gemm_bt(const bf16* __restrict__ Abase, const bf16* __restrict__ Bbase,
             void* __restrict__ Cbase, const float* __restrict__ biasBase,
             int K, int lda, int ldb, int ldc, int Nvalid,
             int zb0, int zdiv,
             long sAq, long sAr, long sAz,
             long sBq, long sBr, long sBz,
             long sCq, long sCr, long sCz,
             long sBiasq)
{
    int bz = blockIdx.z;
    int za = zb0 + bz;
    int zq = za / zdiv, zr = za - zq*zdiv;
    const bf16* A = Abase + (long)zq*sAq + (long)zr*sAr + (long)bz*sAz;
    const bf16* B = Bbase + (long)zq*sBq + (long)zr*sBr + (long)bz*sBz;
    const float* bias = biasBase ? (biasBase + (long)zq*sBiasq) : nullptr;
    long coff = (long)zq*sCq + (long)zr*sCr + (long)bz*sCz;

    __shared__ bf16 As[128*32];
    __shared__ bf16 Bs[128*32];

    int nwg  = gridDim.x * gridDim.y;
    int orig = blockIdx.y * gridDim.x + blockIdx.x;
    int q8 = nwg >> 3, r8 = nwg & 7;
    int xcd = orig & 7, idx = orig >> 3;
    int wg = (xcd < r8 ? xcd*(q8+1) : r8*(q8+1) + (xcd-r8)*q8) + idx;
    int bn = wg % gridDim.x, bm = wg / gridDim.x;

    int t = threadIdx.x;
    int wave = t >> 6, lane = t & 63;
    int wm = (wave >> 1) << 6;   // 0 or 64
    int wn = (wave & 1) << 6;
    int lr = lane & 15, lg = lane >> 4;

    f32x4 acc[4][4] = {};

    int arow = t >> 2;              // 0..63
    int acol = (t & 3) << 3;        // 0,8,16,24
    const bf16* Ag0 = A + (long)(bm*128 + arow)*lda + acol;
    const bf16* Ag1 = Ag0 + (long)64*lda;
    const bf16* Bg0 = B + (long)(bn*128 + arow)*ldb + acol;
    const bf16* Bg1 = Bg0 + (long)64*ldb;
    bf16* Al = As + t*8;
    bf16* Bl = Bs + t*8;

    for (int k0 = 0; k0 < K; k0 += 32) {
        __syncthreads();
        gload16(Ag0, Al);
        gload16(Ag1, Al + 64*32);
        gload16(Bg0, Bl);
        gload16(Bg1, Bl + 64*32);
        Ag0 += 32; Ag1 += 32; Bg0 += 32; Bg1 += 32;
        __syncthreads();
        short8 af[4], bfr[4];
        #pragma unroll
        for (int m=0;m<4;m++) af[m]  = *(short8*)&As[(wm + m*16 + lr)*32 + lg*8];
        #pragma unroll
        for (int n=0;n<4;n++) bfr[n] = *(short8*)&Bs[(wn + n*16 + lr)*32 + lg*8];
        #pragma unroll
        for (int m=0;m<4;m++)
            #pragma unroll
            for (int n=0;n<4;n++)
                acc[m][n] = __builtin_amdgcn_mfma_f32_16x16x32_bf16(af[m], bfr[n], acc[m][n], 0,0,0);
    }

    // epilogue: C/D layout col=lane&15, row=(lane>>4)*4 + i  [m89/m91 verified]
    #pragma unroll
    for (int m=0;m<4;m++){
        #pragma unroll
        for (int n=0;n<4;n++){
            int col = bn*128 + wn + n*16 + lr;
            float bcol = 0.f;
            if constexpr (EPI==0||EPI==4) bcol = bias[col];
            #pragma unroll
            for (int i=0;i<4;i++){
                long row = (long)bm*128 + wm + m*16 + lg*4 + i;
                float v = acc[m][n][i];
                if constexpr (EPI==0){
                    ((bf16*)Cbase + coff)[row*ldc+col] = f2bf(v + bcol);
                } else if constexpr (EPI==4){
                    ((float*)Cbase + coff)[row*ldc+col] = v*0.125f + bcol;
                } else if constexpr (EPI==5){
                    if (col < Nvalid) ((bf16*)Cbase + coff)[row*ldc+col] = f2bf(v);
                } else {
                    unsafeAtomicAdd((float*)Cbase + coff + row*ldc + col, v);
                }
            }
        }
    }
}

// ---------------------------------------------------------------------------
// Fused per-head FFN1 + head reduction:
// S[t][i] = sum_h w_a[h] * gelu( w_kp[h]*(ctx2[t] @ WcT[i])_h + bhc[h][i] )
// A = ctx2 [2048][768] (K-major, head h occupies K-cols h*64..h*64+63)
// B = WcT [3072][768] (K-major, same head chunking)
// 128x128 tile, BK=32; per head = 2 K-steps, then gelu-merge, acc reset.
// ---------------------------------------------------------------------------
__global__ __launch_bounds__(256)
void gemm_heads(const bf16* __restrict__ A, const bf16* __restrict__ B,
                bf16* __restrict__ S, const float* __restrict__ bhc,
                const float* __restrict__ w_kp, const float* __restrict__ w_a)
{
    __shared__ bf16 As[128*32];
    __shared__ bf16 Bs[128*32];

    int nwg  = gridDim.x * gridDim.y;
    int orig = blockIdx.y * gridDim.x + blockIdx.x;
    int q8 = nwg >> 3, r8 = nwg & 7;
    int xcd = orig & 7, idx = orig >> 3;
    int wg = (xcd < r8 ? xcd*(q8+1) : r8*(q8+1) + (xcd-r8)*q8) + idx;
    int bn = wg % gridDim.x, bm = wg / gridDim.x;

    int t = threadIdx.x;
    int wave = t >> 6, lane = t & 63;
    int wm = (wave >> 1) << 6;
    int wn = (wave & 1) << 6;
    int lr = lane & 15, lg = lane >> 4;

    f32x4 acc[4][4] = {};
    f32x4 sacc[4][4] = {};

    int arow = t >> 2;
    int acol = (t & 3) << 3;
    const bf16* Ag0 = A + (long)(bm*128 + arow)*HIDN + acol;
    const bf16* Ag1 = Ag0 + (long)64*HIDN;
    const bf16* Bg0 = B + (long)(bn*128 + arow)*HIDN + acol;
    const bf16* Bg1 = Bg0 + (long)64*HIDN;
    bf16* Al = As + t*8;
    bf16* Bl = Bs + t*8;

    int cols[4];
    #pragma unroll
    for (int n=0;n<4;n++) cols[n] = bn*128 + wn + n*16 + lr;

    for (int h = 0; h < NH; ++h){
        #pragma unroll
        for (int kk = 0; kk < 2; ++kk){
            __syncthreads();
            gload16(Ag0, Al);
            gload16(Ag1, Al + 64*32);
            gload16(Bg0, Bl);
            gload16(Bg1, Bl + 64*32);
            Ag0 += 32; Ag1 += 32; Bg0 += 32; Bg1 += 32;
            __syncthreads();
            short8 af[4], bfr[4];
            #pragma unroll
            for (int m=0;m<4;m++) af[m]  = *(short8*)&As[(wm + m*16 + lr)*32 + lg*8];
            #pragma unroll
            for (int n=0;n<4;n++) bfr[n] = *(short8*)&Bs[(wn + n*16 + lr)*32 + lg*8];
            #pragma unroll
            for (int m=0;m<4;m++)
                #pragma unroll
                for (int n=0;n<4;n++)
                    acc[m][n] = __builtin_amdgcn_mfma_f32_16x16x32_bf16(af[m], bfr[n], acc[m][n], 0,0,0);
        }
        float wk = w_kp[h], wa = w_a[h];
        float bh[4];
        #pragma unroll
        for (int n=0;n<4;n++) bh[n] = bhc[h*ISZ + cols[n]];
        #pragma unroll
        for (int m=0;m<4;m++)
            #pragma unroll
            for (int n=0;n<4;n++)
                #pragma unroll
                for (int i=0;i<4;i++){
                    float v = wk*acc[m][n][i] + bh[n];
                    sacc[m][n][i] += wa * gelu_f(v);
                    acc[m][n][i] = 0.f;
                }
    }

    #pragma unroll
    for (int m=0;m<4;m++)
        #pragma unroll
        for (int n=0;n<4;n++)
            #pragma unroll
            for (int i=0;i<4;i++){
                long row = (long)bm*128 + wm + m*16 + lg*4 + i;
                S[row*ISZ + cols[n]] = f2bf(sacc[m][n][i]);
            }
}

// bhc[h][i] = w_kp[h]*(bo_h @ Wi)[i] + bi[i]
__global__ void bhc_kernel(const float* __restrict__ bo, const float* __restrict__ Wi,
                           const float* __restrict__ bi, const float* __restrict__ w_kp,
                           float* __restrict__ bhc)
{
    int i = blockIdx.x*256 + threadIdx.x;
    if (i >= NH*ISZ) return;
    int h = i / ISZ, c = i - h*ISZ;
    float s = 0.f;
    for (int m = 0; m < HIDN; ++m) s += bo[h*HIDN + m] * Wi[(long)m*ISZ + c];
    bhc[i] = w_kp[h]*s + bi[c];
}

// ---------------------------------------------------------------------------
__global__ __launch_bounds__(256)
void transpose_cvt(const float* __restrict__ src, bf16* __restrict__ dst,
                   int R, int C, long sSrcZ, long sDstZ)
{
    __shared__ float tile[32][33];
    src += (long)blockIdx.z * sSrcZ;
    dst += (long)blockIdx.z * sDstZ;
    int c0 = blockIdx.x*32, r0 = blockIdx.y*32;
    int tx = threadIdx.x & 31, ty = threadIdx.x >> 5;
    #pragma unroll
    for (int i=0;i<32;i+=8) tile[ty+i][tx] = src[(long)(r0+ty+i)*C + c0+tx];
    __syncthreads();
    #pragma unroll
    for (int i=0;i<32;i+=8) dst[(long)(c0+ty+i)*R + r0+tx] = f2bf(tile[tx][ty+i]);
}

__global__ __launch_bounds__(256)
void transpose_v(const bf16* __restrict__ qkv, bf16* __restrict__ Vt, int zb0)
{
    __shared__ bf16 tile[32][33];
    int za = zb0 + blockIdx.z; int b = za/NH, h = za - b*NH;
    const bf16* src = qkv + (long)b*SEQ*3*HIDN + 2*HIDN + h*HD;
    bf16* dst = Vt + (long)blockIdx.z*128*SEQ;
    int d0 = blockIdx.x*32, s0 = blockIdx.y*32;
    int tx = threadIdx.x & 31, ty = threadIdx.x >> 5;
    #pragma unroll
    for (int i=0;i<32;i+=8) tile[ty+i][tx] = src[(long)(s0+ty+i)*(3*HIDN) + d0+tx];
    __syncthreads();
    #pragma unroll
    for (int i=0;i<32;i+=8) dst[(long)(d0+ty+i)*SEQ + s0+tx] = tile[tx][ty+i];
}

__global__ void cvt_bf16(const float* __restrict__ in, bf16* __restrict__ out, int n){
    int i = blockIdx.x*blockDim.x + threadIdx.x;
    if (i < n) out[i] = f2bf(in[i]);
}

__global__ void concat_bias(const float* __restrict__ bq, const float* __restrict__ bk,
                            const float* __restrict__ bv, float* __restrict__ bqkv){
    int i = blockIdx.x*blockDim.x + threadIdx.x;
    if (i < 3*HIDN) bqkv[i] = (i < HIDN) ? bq[i] : (i < 2*HIDN ? bk[i-HIDN] : bv[i-2*HIDN]);
}

__global__ __launch_bounds__(256)
void softmax_rows(const float* __restrict__ scores, bf16* __restrict__ probs)
{
    __shared__ float red[8];
    long row = blockIdx.x;
    const float* s = scores + row*SEQ;
    bf16* p = probs + row*SEQ;
    int t = threadIdx.x;
    int wave = t>>6, lane = t&63;
    float a = s[t], b2 = s[t+256];
    float m = fmaxf(a,b2);
    #pragma unroll
    for (int o=32;o>0;o>>=1) m = fmaxf(m, __shfl_xor(m,o,64));
    if (lane==0) red[wave]=m;
    __syncthreads();
    m = fmaxf(fmaxf(red[0],red[1]),fmaxf(red[2],red[3]));
    float e0 = __expf(a-m), e1 = __expf(b2-m);
    float sum = e0+e1;
    #pragma unroll
    for (int o=32;o>0;o>>=1) sum += __shfl_xor(sum,o,64);
    __syncthreads();
    if (lane==0) red[4+wave]=sum;
    __syncthreads();
    sum = red[4]+red[5]+red[6]+red[7];
    float inv = 1.0f/sum;
    p[t]     = f2bf(e0*inv);
    p[t+256] = f2bf(e1*inv);
}

__global__ __launch_bounds__(256)
void add_ln(const float* __restrict__ hidden, const float* __restrict__ out_acc,
            const float* __restrict__ bout, const float* __restrict__ w_a,
            const float* __restrict__ gamma, const float* __restrict__ beta,
            float* __restrict__ out)
{
    __shared__ float red[8];
    int row = blockIdx.x;
    int t = threadIdx.x;
    int wave = t>>6, lane = t&63;
    float swa = 0.f;
    #pragma unroll
    for (int h=0;h<NH;h++) swa += w_a[h];
    float x[3];
    float sum = 0.f;
    #pragma unroll
    for (int j=0;j<3;j++){
        int c = j*256 + t;
        x[j] = hidden[(long)row*HIDN + c] + out_acc[(long)row*HIDN + c] + swa*bout[c];
        sum += x[j];
    }
    #pragma unroll
    for (int o=32;o>0;o>>=1) sum += __shfl_xor(sum,o,64);
    if (lane==0) red[wave]=sum;
    __syncthreads();
    sum = red[0]+red[1]+red[2]+red[3];
    float u = sum * (1.0f/768.0f);
    float vs = 0.f;
    #pragma unroll
    for (int j=0;j<3;j++){ float d = x[j]-u; vs += d*d; }
    #pragma unroll
    for (int o=32;o>0;o>>=1) vs += __shfl_xor(vs,o,64);
    __syncthreads();
    if (lane==0) red[4+wave]=vs;
    __syncthreads();
    vs = red[4]+red[5]+red[6]+red[7];
    float rstd = rsqrtf(vs*(1.0f/768.0f) + 1e-12f);
    #pragma unroll
    for (int j=0;j<3;j++){
        int c = j*256 + t;
        out[(long)row*HIDN + c] = gamma[c]*(x[j]-u)*rstd + beta[c];
    }
}

extern "C" void kernel_launch(void* const* d_in, const int* in_sizes, int n_in,
                              void* d_out, int out_size, void* d_ws, size_t ws_size,
                              hipStream_t stream)
{
    const float* hidden = (const float*)d_in[0];
    const float* mask   = (const float*)d_in[1];
    const float* Wq = (const float*)d_in[2];
    const float* bq = (const float*)d_in[3];
    const float* Wk = (const float*)d_in[4];
    const float* bk = (const float*)d_in[5];
    const float* Wv = (const float*)d_in[6];
    const float* bv = (const float*)d_in[7];
    const float* Wo = (const float*)d_in[8];
    const float* bo = (const float*)d_in[9];
    const float* w_kp = (const float*)d_in[10];
    const float* w_a  = (const float*)d_in[11];
    const float* Wi = (const float*)d_in[12];
    const float* bi = (const float*)d_in[13];
    const float* Wout = (const float*)d_in[14];
    const float* boutp = (const float*)d_in[15];
    const float* gamma = (const float*)d_in[16];
    const float* beta  = (const float*)d_in[17];
    float* out = (float*)d_out;

    char* w = (char*)d_ws;
    auto alloc = [&](size_t bytes)->char* {
        char* p = w; w += (bytes + 255) & ~(size_t)255; return p;
    };
    bf16*  hbf    = (bf16*) alloc((size_t)NTOK*HIDN*2);
    bf16*  WqkvT  = (bf16*) alloc((size_t)3*HIDN*HIDN*2);
    float* bqkv   = (float*)alloc((size_t)3*HIDN*4);
    bf16*  WiT    = (bf16*) alloc((size_t)ISZ*HIDN*2);
    bf16*  WoutT  = (bf16*) alloc((size_t)HIDN*ISZ*2);
    bf16*  Wobf   = (bf16*) alloc((size_t)HIDN*HIDN*2);     // Wo stacked [768][768]
    bf16*  WcT    = (bf16*) alloc((size_t)ISZ*HIDN*2);      // (Wo@Wi)^T  [3072][768]
    float* bhc    = (float*)alloc((size_t)NH*ISZ*4);        // [12][3072]
    bf16*  qkv    = (bf16*) alloc((size_t)NTOK*3*HIDN*2);
    bf16*  ctx2   = (bf16*) alloc((size_t)NTOK*HIDN*2);     // [2048][h*64+d]
    bf16*  Sbuf   = (bf16*) alloc((size_t)NTOK*ISZ*2);      // [2048][3072]
    float* out_acc= (float*)alloc((size_t)NTOK*HIDN*4);
    size_t fixed = (size_t)(w - (char*)d_ws);
    size_t avail = ws_size > fixed ? ws_size - fixed : 0;

    const size_t perZ = (size_t)SEQ*SEQ*4 + (size_t)SEQ*SEQ*2 + (size_t)128*SEQ*2;
    int ZB = 48;
    while (ZB > 6 && perZ*(size_t)ZB > avail) ZB >>= 1;

    char* big = w;
    float* scores = (float*)big;
    bf16*  probs  = (bf16*)(big + (size_t)ZB*SEQ*SEQ*4);
    bf16*  Vt     = (bf16*)(big + (size_t)ZB*SEQ*SEQ*4 + (size_t)ZB*SEQ*SEQ*2);

    // ---- prep: convert / transpose weights ----
    cvt_bf16<<<(NTOK*HIDN+255)/256, 256, 0, stream>>>(hidden, hbf, NTOK*HIDN);
    cvt_bf16<<<(HIDN*HIDN+255)/256, 256, 0, stream>>>(Wo, Wobf, HIDN*HIDN);
    concat_bias<<<(3*HIDN+255)/256, 256, 0, stream>>>(bq, bk, bv, bqkv);
    transpose_cvt<<<dim3(HIDN/32, HIDN/32, 1), 256, 0, stream>>>(Wq, WqkvT,              HIDN, HIDN, 0, 0);
    transpose_cvt<<<dim3(HIDN/32, HIDN/32, 1), 256, 0, stream>>>(Wk, WqkvT + HIDN*HIDN,  HIDN, HIDN, 0, 0);
    transpose_cvt<<<dim3(HIDN/32, HIDN/32, 1), 256, 0, stream>>>(Wv, WqkvT + 2*HIDN*HIDN,HIDN, HIDN, 0, 0);
    transpose_cvt<<<dim3(ISZ/32,  HIDN/32, 1), 256, 0, stream>>>(Wi,   WiT,   HIDN, ISZ, 0, 0);
    transpose_cvt<<<dim3(HIDN/32, ISZ/32,  1), 256, 0, stream>>>(Wout, WoutT, ISZ, HIDN, 0, 0);
    bhc_kernel<<<(NH*ISZ+255)/256, 256, 0, stream>>>(bo, Wi, bi, w_kp, bhc);

    // WcT[i][hd] = sum_m Wi[m][i]*Wo[hd][m]  : A=WiT [3072][768], B=Wobf [768][768]
    gemm_bt<5><<<dim3(HIDN/128, ISZ/128, 1), 256, 0, stream>>>(
        WiT, Wobf, WcT, nullptr,
        HIDN, HIDN, HIDN, HIDN, HIDN,
        0, 1,
        0,0,0, 0,0,0, 0,0,0, 0);

    // ---- QKV projection: [2048,768] @ [2304,768]^T ----
    gemm_bt<0><<<dim3(3*HIDN/128, NTOK/128, 1), 256, 0, stream>>>(
        hbf, WqkvT, qkv, bqkv,
        HIDN, HIDN, HIDN, 3*HIDN, 3*HIDN,
        0, 1,
        0,0,0, 0,0,0, 0,0,0, 0);

    // ---- attention ----
    hipMemsetAsync(Vt, 0, (size_t)ZB*128*SEQ*2, stream);
    for (int g = 0; g < 48; g += ZB) {
        transpose_v<<<dim3(2,16,ZB), 256, 0, stream>>>(qkv, Vt, g);
        gemm_bt<4><<<dim3(SEQ/128, SEQ/128, ZB), 256, 0, stream>>>(
            qkv, qkv + HIDN, scores, mask,
            HD, 3*HIDN, 3*HIDN, SEQ, SEQ,
            g, NH,
            (long)SEQ*3*HIDN, HD, 0,
            (long)SEQ*3*HIDN, HD, 0,
            0, 0, (long)SEQ*SEQ,
            SEQ);
        softmax_rows<<<ZB*SEQ, 256, 0, stream>>>(scores, probs);
        // ctx2[(b*512+s)][h*64+d] = probs @ V
        gemm_bt<5><<<dim3(1, SEQ/128, ZB), 256, 0, stream>>>(
            probs, Vt, ctx2, nullptr,
            SEQ, SEQ, SEQ, HIDN, HD,
            g, NH,
            0, 0, (long)SEQ*SEQ,
            0, 0, (long)128*SEQ,
            (long)SEQ*HIDN, HD, 0,
            0);
    }

    // ---- fused per-head FFN1 + head-reduce -> S ----
    gemm_heads<<<dim3(ISZ/128, NTOK/128, 1), 256, 0, stream>>>(
        ctx2, WcT, Sbuf, bhc, w_kp, w_a);

    // ---- FFN2': out_acc = S @ WoutT^T  (split-K=4, atomic f32) ----
    hipMemsetAsync(out_acc, 0, (size_t)NTOK*HIDN*4, stream);
    gemm_bt<6><<<dim3(HIDN/128, NTOK/128, 4), 256, 0, stream>>>(
        Sbuf, WoutT, out_acc, nullptr,
        ISZ/4, ISZ, ISZ, HIDN, HIDN,
        0, 1,
        (long)(ISZ/4), 0, 0,
        (long)(ISZ/4), 0, 0,
        0, 0, 0,
        0);

    // ---- residual + sum(w_a)*bout + LayerNorm ----
    add_ln<<<NTOK, 256, 0, stream>>>(hidden, out_acc, boutp, w_a, gamma, beta, out);
}

// Round 6
// 269.524 us; speedup vs baseline: 1.8927x; 1.1934x over previous
//
#include <hip/hip_runtime.h>
#include <hip/hip_bf16.h>
#include <math.h>

typedef __hip_bfloat16 bf16;
typedef __attribute__((ext_vector_type(4))) float f32x4;
typedef __attribute__((ext_vector_type(8))) short short8;

#define HIDN 768
#define NTOK 2048   // B*S
#define NH 12
#define HD 64
#define ISZ 3072
#define SEQ 512

__device__ __forceinline__ bf16 f2bf(float x){ return __float2bfloat16(x); }
__device__ __forceinline__ float gelu_f(float x){ return 0.5f*x*(1.0f + erff(x*0.70710678118654752f)); }
// tanh-approx gelu in stable sigmoid form: x * sigmoid(2t), t = x(c0 + c1 x^2)
__device__ __forceinline__ float gelu_fast(float x){
    float t2 = 2.0f*x*(0.7978845608028654f + 0.0356774081f*x*x);
    return x / (1.0f + __expf(-t2));
}

// async global->LDS, 16B per lane (LDS dest = wave base + lane*16)
__device__ __forceinline__ void gload16(const bf16* g, bf16* l){
    __builtin_amdgcn_global_load_lds(
        (const __attribute__((address_space(1))) unsigned int*)g,
        (__attribute__((address_space(3))) unsigned int*)l,
        16, 0, 0);
}

// ---------------------------------------------------------------------------
// Generic bf16 GEMM (m97 structure): C = A[M,K] @ B[N,K]^T, both K-major.
// 128x128 tile, BK=32, 256 threads = 4 waves. global_load_lds staging.
// EPI: 0 = bias, bf16 out              (QKV)
//      4 = v*0.125 + bias[col], f32    (attention scores + mask)
//      5 = bf16 out, col<Nvalid guard  (PV, WcT)
//      6 = unsafeAtomicAdd f32, no scale (FFN2' split-K)
// ---------------------------------------------------------------------------
template<int EPI>
__global__ __launch_bounds__(256)
void gemm_bt(const bf16* __restrict__ Abase, const bf16* __restrict__ Bbase,
             void* __restrict__ Cbase, const float* __restrict__ biasBase,
             int K, int lda, int ldb, int ldc, int Nvalid,
             int zb0, int zdiv,
             long sAq, long sAr, long sAz,
             long sBq, long sBr, long sBz,
             long sCq, long sCr, long sCz,
             long sBiasq)
{
    int bz = blockIdx.z;
    int za = zb0 + bz;
    int zq = za / zdiv, zr = za - zq*zdiv;
    const bf16* A = Abase + (long)zq*sAq + (long)zr*sAr + (long)bz*sAz;
    const bf16* B = Bbase + (long)zq*sBq + (long)zr*sBr + (long)bz*sBz;
    const float* bias = biasBase ? (biasBase + (long)zq*sBiasq) : nullptr;
    long coff = (long)zq*sCq + (long)zr*sCr + (long)bz*sCz;

    __shared__ bf16 As[128*32];
    __shared__ bf16 Bs[128*32];

    int nwg  = gridDim.x * gridDim.y;
    int orig = blockIdx.y * gridDim.x + blockIdx.x;
    int q8 = nwg >> 3, r8 = nwg & 7;
    int xcd = orig & 7, idx = orig >> 3;
    int wg = (xcd < r8 ? xcd*(q8+1) : r8*(q8+1) + (xcd-r8)*q8) + idx;
    int bn = wg % gridDim.x, bm = wg / gridDim.x;

    int t = threadIdx.x;
    int wave = t >> 6, lane = t & 63;
    int wm = (wave >> 1) << 6;   // 0 or 64
    int wn = (wave & 1) << 6;
    int lr = lane & 15, lg = lane >> 4;

    f32x4 acc[4][4] = {};

    int arow = t >> 2;              // 0..63
    int acol = (t & 3) << 3;        // 0,8,16,24
    const bf16* Ag0 = A + (long)(bm*128 + arow)*lda + acol;
    const bf16* Ag1 = Ag0 + (long)64*lda;
    const bf16* Bg0 = B + (long)(bn*128 + arow)*ldb + acol;
    const bf16* Bg1 = Bg0 + (long)64*ldb;
    bf16* Al = As + t*8;
    bf16* Bl = Bs + t*8;

    for (int k0 = 0; k0 < K; k0 += 32) {
        __syncthreads();
        gload16(Ag0, Al);
        gload16(Ag1, Al + 64*32);
        gload16(Bg0, Bl);
        gload16(Bg1, Bl + 64*32);
        Ag0 += 32; Ag1 += 32; Bg0 += 32; Bg1 += 32;
        __syncthreads();
        short8 af[4], bfr[4];
        #pragma unroll
        for (int m=0;m<4;m++) af[m]  = *(short8*)&As[(wm + m*16 + lr)*32 + lg*8];
        #pragma unroll
        for (int n=0;n<4;n++) bfr[n] = *(short8*)&Bs[(wn + n*16 + lr)*32 + lg*8];
        #pragma unroll
        for (int m=0;m<4;m++)
            #pragma unroll
            for (int n=0;n<4;n++)
                acc[m][n] = __builtin_amdgcn_mfma_f32_16x16x32_bf16(af[m], bfr[n], acc[m][n], 0,0,0);
    }

    // epilogue: C/D layout col=lane&15, row=(lane>>4)*4 + i  [m89/m91 verified]
    #pragma unroll
    for (int m=0;m<4;m++){
        #pragma unroll
        for (int n=0;n<4;n++){
            int col = bn*128 + wn + n*16 + lr;
            float bcol = 0.f;
            if constexpr (EPI==0||EPI==4) bcol = bias[col];
            #pragma unroll
            for (int i=0;i<4;i++){
                long row = (long)bm*128 + wm + m*16 + lg*4 + i;
                float v = acc[m][n][i];
                if constexpr (EPI==0){
                    ((bf16*)Cbase + coff)[row*ldc+col] = f2bf(v + bcol);
                } else if constexpr (EPI==4){
                    ((float*)Cbase + coff)[row*ldc+col] = v*0.125f + bcol;
                } else if constexpr (EPI==5){
                    if (col < Nvalid) ((bf16*)Cbase + coff)[row*ldc+col] = f2bf(v);
                } else {
                    unsafeAtomicAdd((float*)Cbase + coff + row*ldc + col, v);
                }
            }
        }
    }
}

// ---------------------------------------------------------------------------
// Fused per-head FFN1 + head reduction (v2):
// S[t][i] = sum_h w_a[h] * gelu( w_kp[h]*(ctx2[t] @ WcT[i])_h + bhc[h][i] )
// 512 threads = 8 waves (4M x 2N), wave = 32x64 of the 128x128 tile.
// Per head: BK=64 single stage (XOR-swizzled LDS, pre-swizzled global src),
// prev head's gelu-merge placed between load-issue and barrier (hides HBM lat).
// ---------------------------------------------------------------------------
__global__ __launch_bounds__(512)
void gemm_heads(const bf16* __restrict__ A, const bf16* __restrict__ B,
                bf16* __restrict__ S, const float* __restrict__ bhc,
                const float* __restrict__ w_kp, const float* __restrict__ w_a)
{
    __shared__ __align__(16) bf16 As[128*64];   // 16 KB, row stride 128 B
    __shared__ __align__(16) bf16 Bs[128*64];   // 16 KB

    int nwg  = gridDim.x * gridDim.y;
    int orig = blockIdx.y * gridDim.x + blockIdx.x;
    int q8 = nwg >> 3, r8 = nwg & 7;
    int xcd = orig & 7, idx = orig >> 3;
    int wg = (xcd < r8 ? xcd*(q8+1) : r8*(q8+1) + (xcd-r8)*q8) + idx;
    int bn = wg % gridDim.x, bm = wg / gridDim.x;

    int t = threadIdx.x;
    int wave = t >> 6, lane = t & 63;
    int wm = (wave >> 1) << 5;    // 0,32,64,96
    int wn = (wave & 1) << 6;     // 0,64
    int lr = lane & 15, lg = lane >> 4;
    int x7 = lr & 7;

    // staging: thread t -> row (t>>3) of each 64-row half, pre-swizzled granule
    int srow = t >> 3;                       // 0..63
    int glog = (t & 7) ^ (srow & 7);         // source granule (so LDS phys g holds logical g^row&7)
    const bf16* Ag0 = A + (long)(bm*128 + srow)*HIDN + glog*8;
    const bf16* Ag1 = Ag0 + (long)64*HIDN;
    const bf16* Bg0 = B + (long)(bn*128 + srow)*HIDN + glog*8;
    const bf16* Bg1 = Bg0 + (long)64*HIDN;

    f32x4 acc[2][4] = {};
    f32x4 sacc[2][4] = {};

    int cols[4];
    #pragma unroll
    for (int n=0;n<4;n++) cols[n] = bn*128 + wn + n*16 + lr;

    // ds_read byte offsets: phys granule = (kk*4+lg) ^ (row&7), row&7 == lr&7
    int gb0 = ((lg    ) ^ x7) << 4;
    int gb1 = ((4 | lg) ^ x7) << 4;

    for (int h = 0; h < NH; ++h){
        __syncthreads();                       // prev iter's ds_reads done
        gload16(Ag0, As + t*8);                // A rows 0-63  (this head's 64 K-cols)
        gload16(Ag1, As + 4096 + t*8);         // A rows 64-127
        gload16(Bg0, Bs + t*8);
        gload16(Bg1, Bs + 4096 + t*8);
        Ag0 += 64; Ag1 += 64; Bg0 += 64; Bg1 += 64;

        if (h > 0){                            // gelu-merge head h-1: hides load latency
            float wk = w_kp[h-1], wa = w_a[h-1];
            float bh[4];
            #pragma unroll
            for (int n=0;n<4;n++) bh[n] = bhc[(h-1)*ISZ + cols[n]];
            #pragma unroll
            for (int m=0;m<2;m++)
                #pragma unroll
                for (int n=0;n<4;n++)
                    #pragma unroll
                    for (int i=0;i<4;i++){
                        float v = wk*acc[m][n][i] + bh[n];
                        sacc[m][n][i] += wa * gelu_fast(v);
                        acc[m][n][i] = 0.f;
                    }
        }
        __syncthreads();                       // drains vmcnt -> LDS ready

        short8 af[2][2], bfr[4][2];
        #pragma unroll
        for (int m=0;m<2;m++){
            const char* pr = (const char*)As + (wm + m*16 + lr)*128;
            af[m][0] = *(const short8*)(pr + gb0);
            af[m][1] = *(const short8*)(pr + gb1);
        }
        #pragma unroll
        for (int n=0;n<4;n++){
            const char* pr = (const char*)Bs + (wn + n*16 + lr)*128;
            bfr[n][0] = *(const short8*)(pr + gb0);
            bfr[n][1] = *(const short8*)(pr + gb1);
        }
        #pragma unroll
        for (int m=0;m<2;m++)
            #pragma unroll
            for (int n=0;n<4;n++)
                #pragma unroll
                for (int kk=0;kk<2;kk++)
                    acc[m][n] = __builtin_amdgcn_mfma_f32_16x16x32_bf16(af[m][kk], bfr[n][kk], acc[m][n], 0,0,0);
    }

    // final head's merge
    {
        float wk = w_kp[NH-1], wa = w_a[NH-1];
        float bh[4];
        #pragma unroll
        for (int n=0;n<4;n++) bh[n] = bhc[(NH-1)*ISZ + cols[n]];
        #pragma unroll
        for (int m=0;m<2;m++)
            #pragma unroll
            for (int n=0;n<4;n++)
                #pragma unroll
                for (int i=0;i<4;i++){
                    float v = wk*acc[m][n][i] + bh[n];
                    sacc[m][n][i] += wa * gelu_fast(v);
                }
    }

    #pragma unroll
    for (int m=0;m<2;m++)
        #pragma unroll
        for (int n=0;n<4;n++)
            #pragma unroll
            for (int i=0;i<4;i++){
                long row = (long)bm*128 + wm + m*16 + lg*4 + i;
                S[row*ISZ + cols[n]] = f2bf(sacc[m][n][i]);
            }
}

// bhc[h][i] = w_kp[h]*(bo_h @ Wi)[i] + bi[i]
__global__ void bhc_kernel(const float* __restrict__ bo, const float* __restrict__ Wi,
                           const float* __restrict__ bi, const float* __restrict__ w_kp,
                           float* __restrict__ bhc)
{
    int i = blockIdx.x*256 + threadIdx.x;
    if (i >= NH*ISZ) return;
    int h = i / ISZ, c = i - h*ISZ;
    float s = 0.f;
    for (int m = 0; m < HIDN; ++m) s += bo[h*HIDN + m] * Wi[(long)m*ISZ + c];
    bhc[i] = w_kp[h]*s + bi[c];
}

// ---------------------------------------------------------------------------
__global__ __launch_bounds__(256)
void transpose_cvt(const float* __restrict__ src, bf16* __restrict__ dst,
                   int R, int C, long sSrcZ, long sDstZ)
{
    __shared__ float tile[32][33];
    src += (long)blockIdx.z * sSrcZ;
    dst += (long)blockIdx.z * sDstZ;
    int c0 = blockIdx.x*32, r0 = blockIdx.y*32;
    int tx = threadIdx.x & 31, ty = threadIdx.x >> 5;
    #pragma unroll
    for (int i=0;i<32;i+=8) tile[ty+i][tx] = src[(long)(r0+ty+i)*C + c0+tx];
    __syncthreads();
    #pragma unroll
    for (int i=0;i<32;i+=8) dst[(long)(c0+ty+i)*R + r0+tx] = f2bf(tile[tx][ty+i]);
}

__global__ __launch_bounds__(256)
void transpose_v(const bf16* __restrict__ qkv, bf16* __restrict__ Vt, int zb0)
{
    __shared__ bf16 tile[32][33];
    int za = zb0 + blockIdx.z; int b = za/NH, h = za - b*NH;
    const bf16* src = qkv + (long)b*SEQ*3*HIDN + 2*HIDN + h*HD;
    bf16* dst = Vt + (long)blockIdx.z*128*SEQ;
    int d0 = blockIdx.x*32, s0 = blockIdx.y*32;
    int tx = threadIdx.x & 31, ty = threadIdx.x >> 5;
    #pragma unroll
    for (int i=0;i<32;i+=8) tile[ty+i][tx] = src[(long)(s0+ty+i)*(3*HIDN) + d0+tx];
    __syncthreads();
    #pragma unroll
    for (int i=0;i<32;i+=8) dst[(long)(d0+ty+i)*SEQ + s0+tx] = tile[tx][ty+i];
}

__global__ void cvt_bf16(const float* __restrict__ in, bf16* __restrict__ out, int n){
    int i = blockIdx.x*blockDim.x + threadIdx.x;
    if (i < n) out[i] = f2bf(in[i]);
}

__global__ void concat_bias(const float* __restrict__ bq, const float* __restrict__ bk,
                            const float* __restrict__ bv, float* __restrict__ bqkv){
    int i = blockIdx.x*blockDim.x + threadIdx.x;
    if (i < 3*HIDN) bqkv[i] = (i < HIDN) ? bq[i] : (i < 2*HIDN ? bk[i-HIDN] : bv[i-2*HIDN]);
}

__global__ __launch_bounds__(256)
void softmax_rows(const float* __restrict__ scores, bf16* __restrict__ probs)
{
    __shared__ float red[8];
    long row = blockIdx.x;
    const float* s = scores + row*SEQ;
    bf16* p = probs + row*SEQ;
    int t = threadIdx.x;
    int wave = t>>6, lane = t&63;
    float a = s[t], b2 = s[t+256];
    float m = fmaxf(a,b2);
    #pragma unroll
    for (int o=32;o>0;o>>=1) m = fmaxf(m, __shfl_xor(m,o,64));
    if (lane==0) red[wave]=m;
    __syncthreads();
    m = fmaxf(fmaxf(red[0],red[1]),fmaxf(red[2],red[3]));
    float e0 = __expf(a-m), e1 = __expf(b2-m);
    float sum = e0+e1;
    #pragma unroll
    for (int o=32;o>0;o>>=1) sum += __shfl_xor(sum,o,64);
    __syncthreads();
    if (lane==0) red[4+wave]=sum;
    __syncthreads();
    sum = red[4]+red[5]+red[6]+red[7];
    float inv = 1.0f/sum;
    p[t]     = f2bf(e0*inv);
    p[t+256] = f2bf(e1*inv);
}

__global__ __launch_bounds__(256)
void add_ln(const float* __restrict__ hidden, const float* __restrict__ out_acc,
            const float* __restrict__ bout, const float* __restrict__ w_a,
            const float* __restrict__ gamma, const float* __restrict__ beta,
            float* __restrict__ out)
{
    __shared__ float red[8];
    int row = blockIdx.x;
    int t = threadIdx.x;
    int wave = t>>6, lane = t&63;
    float swa = 0.f;
    #pragma unroll
    for (int h=0;h<NH;h++) swa += w_a[h];
    float x[3];
    float sum = 0.f;
    #pragma unroll
    for (int j=0;j<3;j++){
        int c = j*256 + t;
        x[j] = hidden[(long)row*HIDN + c] + out_acc[(long)row*HIDN + c] + swa*bout[c];
        sum += x[j];
    }
    #pragma unroll
    for (int o=32;o>0;o>>=1) sum += __shfl_xor(sum,o,64);
    if (lane==0) red[wave]=sum;
    __syncthreads();
    sum = red[0]+red[1]+red[2]+red[3];
    float u = sum * (1.0f/768.0f);
    float vs = 0.f;
    #pragma unroll
    for (int j=0;j<3;j++){ float d = x[j]-u; vs += d*d; }
    #pragma unroll
    for (int o=32;o>0;o>>=1) vs += __shfl_xor(vs,o,64);
    __syncthreads();
    if (lane==0) red[4+wave]=vs;
    __syncthreads();
    vs = red[4]+red[5]+red[6]+red[7];
    float rstd = rsqrtf(vs*(1.0f/768.0f) + 1e-12f);
    #pragma unroll
    for (int j=0;j<3;j++){
        int c = j*256 + t;
        out[(long)row*HIDN + c] = gamma[c]*(x[j]-u)*rstd + beta[c];
    }
}

extern "C" void kernel_launch(void* const* d_in, const int* in_sizes, int n_in,
                              void* d_out, int out_size, void* d_ws, size_t ws_size,
                              hipStream_t stream)
{
    const float* hidden = (const float*)d_in[0];
    const float* mask   = (const float*)d_in[1];
    const float* Wq = (const float*)d_in[2];
    const float* bq = (const float*)d_in[3];
    const float* Wk = (const float*)d_in[4];
    const float* bk = (const float*)d_in[5];
    const float* Wv = (const float*)d_in[6];
    const float* bv = (const float*)d_in[7];
    const float* Wo = (const float*)d_in[8];
    const float* bo = (const float*)d_in[9];
    const float* w_kp = (const float*)d_in[10];
    const float* w_a  = (const float*)d_in[11];
    const float* Wi = (const float*)d_in[12];
    const float* bi = (const float*)d_in[13];
    const float* Wout = (const float*)d_in[14];
    const float* boutp = (const float*)d_in[15];
    const float* gamma = (const float*)d_in[16];
    const float* beta  = (const float*)d_in[17];
    float* out = (float*)d_out;

    char* w = (char*)d_ws;
    auto alloc = [&](size_t bytes)->char* {
        char* p = w; w += (bytes + 255) & ~(size_t)255; return p;
    };
    bf16*  hbf    = (bf16*) alloc((size_t)NTOK*HIDN*2);
    bf16*  WqkvT  = (bf16*) alloc((size_t)3*HIDN*HIDN*2);
    float* bqkv   = (float*)alloc((size_t)3*HIDN*4);
    bf16*  WiT    = (bf16*) alloc((size_t)ISZ*HIDN*2);
    bf16*  WoutT  = (bf16*) alloc((size_t)HIDN*ISZ*2);
    bf16*  Wobf   = (bf16*) alloc((size_t)HIDN*HIDN*2);     // Wo stacked [768][768]
    bf16*  WcT    = (bf16*) alloc((size_t)ISZ*HIDN*2);      // (Wo@Wi)^T  [3072][768]
    float* bhc    = (float*)alloc((size_t)NH*ISZ*4);        // [12][3072]
    bf16*  qkv    = (bf16*) alloc((size_t)NTOK*3*HIDN*2);
    bf16*  ctx2   = (bf16*) alloc((size_t)NTOK*HIDN*2);     // [2048][h*64+d]
    bf16*  Sbuf   = (bf16*) alloc((size_t)NTOK*ISZ*2);      // [2048][3072]
    float* out_acc= (float*)alloc((size_t)NTOK*HIDN*4);
    size_t fixed = (size_t)(w - (char*)d_ws);
    size_t avail = ws_size > fixed ? ws_size - fixed : 0;

    const size_t perZ = (size_t)SEQ*SEQ*4 + (size_t)SEQ*SEQ*2 + (size_t)128*SEQ*2;
    int ZB = 48;
    while (ZB > 6 && perZ*(size_t)ZB > avail) ZB >>= 1;

    char* big = w;
    float* scores = (float*)big;
    bf16*  probs  = (bf16*)(big + (size_t)ZB*SEQ*SEQ*4);
    bf16*  Vt     = (bf16*)(big + (size_t)ZB*SEQ*SEQ*4 + (size_t)ZB*SEQ*SEQ*2);

    // ---- prep: convert / transpose weights ----
    cvt_bf16<<<(NTOK*HIDN+255)/256, 256, 0, stream>>>(hidden, hbf, NTOK*HIDN);
    cvt_bf16<<<(HIDN*HIDN+255)/256, 256, 0, stream>>>(Wo, Wobf, HIDN*HIDN);
    concat_bias<<<(3*HIDN+255)/256, 256, 0, stream>>>(bq, bk, bv, bqkv);
    transpose_cvt<<<dim3(HIDN/32, HIDN/32, 1), 256, 0, stream>>>(Wq, WqkvT,              HIDN, HIDN, 0, 0);
    transpose_cvt<<<dim3(HIDN/32, HIDN/32, 1), 256, 0, stream>>>(Wk, WqkvT + HIDN*HIDN,  HIDN, HIDN, 0, 0);
    transpose_cvt<<<dim3(HIDN/32, HIDN/32, 1), 256, 0, stream>>>(Wv, WqkvT + 2*HIDN*HIDN,HIDN, HIDN, 0, 0);
    transpose_cvt<<<dim3(ISZ/32,  HIDN/32, 1), 256, 0, stream>>>(Wi,   WiT,   HIDN, ISZ, 0, 0);
    transpose_cvt<<<dim3(HIDN/32, ISZ/32,  1), 256, 0, stream>>>(Wout, WoutT, ISZ, HIDN, 0, 0);
    bhc_kernel<<<(NH*ISZ+255)/256, 256, 0, stream>>>(bo, Wi, bi, w_kp, bhc);

    // WcT[i][hd] = sum_m Wi[m][i]*Wo[hd][m]  : A=WiT [3072][768], B=Wobf [768][768]
    gemm_bt<5><<<dim3(HIDN/128, ISZ/128, 1), 256, 0, stream>>>(
        WiT, Wobf, WcT, nullptr,
        HIDN, HIDN, HIDN, HIDN, HIDN,
        0, 1,
        0,0,0, 0,0,0, 0,0,0, 0);

    // ---- QKV projection: [2048,768] @ [2304,768]^T ----
    gemm_bt<0><<<dim3(3*HIDN/128, NTOK/128, 1), 256, 0, stream>>>(
        hbf, WqkvT, qkv, bqkv,
        HIDN, HIDN, HIDN, 3*HIDN, 3*HIDN,
        0, 1,
        0,0,0, 0,0,0, 0,0,0, 0);

    // ---- attention ----
    hipMemsetAsync(Vt, 0, (size_t)ZB*128*SEQ*2, stream);
    for (int g = 0; g < 48; g += ZB) {
        transpose_v<<<dim3(2,16,ZB), 256, 0, stream>>>(qkv, Vt, g);
        gemm_bt<4><<<dim3(SEQ/128, SEQ/128, ZB), 256, 0, stream>>>(
            qkv, qkv + HIDN, scores, mask,
            HD, 3*HIDN, 3*HIDN, SEQ, SEQ,
            g, NH,
            (long)SEQ*3*HIDN, HD, 0,
            (long)SEQ*3*HIDN, HD, 0,
            0, 0, (long)SEQ*SEQ,
            SEQ);
        softmax_rows<<<ZB*SEQ, 256, 0, stream>>>(scores, probs);
        // ctx2[(b*512+s)][h*64+d] = probs @ V
        gemm_bt<5><<<dim3(1, SEQ/128, ZB), 256, 0, stream>>>(
            probs, Vt, ctx2, nullptr,
            SEQ, SEQ, SEQ, HIDN, HD,
            g, NH,
            0, 0, (long)SEQ*SEQ,
            0, 0, (long)128*SEQ,
            (long)SEQ*HIDN, HD, 0,
            0);
    }

    // ---- fused per-head FFN1 + head-reduce -> S ----
    gemm_heads<<<dim3(ISZ/128, NTOK/128, 1), 512, 0, stream>>>(
        ctx2, WcT, Sbuf, bhc, w_kp, w_a);

    // ---- FFN2': out_acc = S @ WoutT^T  (split-K=4, atomic f32) ----
    hipMemsetAsync(out_acc, 0, (size_t)NTOK*HIDN*4, stream);
    gemm_bt<6><<<dim3(HIDN/128, NTOK/128, 4), 256, 0, stream>>>(
        Sbuf, WoutT, out_acc, nullptr,
        ISZ/4, ISZ, ISZ, HIDN, HIDN,
        0, 1,
        (long)(ISZ/4), 0, 0,
        (long)(ISZ/4), 0, 0,
        0, 0, 0,
        0);

    // ---- residual + sum(w_a)*bout + LayerNorm ----
    add_ln<<<NTOK, 256, 0, stream>>>(hidden, out_acc, boutp, w_a, gamma, beta, out);
}

// Round 7
// 226.079 us; speedup vs baseline: 2.2564x; 1.1922x over previous
//
#include <hip/hip_runtime.h>
#include <hip/hip_bf16.h>
#include <math.h>

typedef __hip_bfloat16 bf16;
typedef __attribute__((ext_vector_type(4))) float f32x4;
typedef __attribute__((ext_vector_type(8))) short short8;

#define HIDN 768
#define NTOK 2048   // B*S
#define NH 12
#define HD 64
#define ISZ 3072
#define SEQ 512

__device__ __forceinline__ bf16 f2bf(float x){ return __float2bfloat16(x); }
// tanh-approx gelu: x*sigmoid(2t), t = x(c0+c1 x^2); exp + fast rcp (no IEEE div)
__device__ __forceinline__ float gelu_fast(float x){
    float t = x * fmaf(x*x, -0.0713548163f, -1.59576912f);   // -(2c0 + 2c1 x^2)x
    float e = __expf(t);
    return x * __builtin_amdgcn_rcpf(1.0f + e);
}

// async global->LDS, 16B per lane (LDS dest = wave base + lane*16)
__device__ __forceinline__ void gload16(const bf16* g, bf16* l){
    __builtin_amdgcn_global_load_lds(
        (const __attribute__((address_space(1))) unsigned int*)g,
        (__attribute__((address_space(3))) unsigned int*)l,
        16, 0, 0);
}

// ---------------------------------------------------------------------------
// Generic bf16 GEMM (m97 structure): C = A[M,K] @ B[N,K]^T, both K-major.
// 128x128 tile, BK=32, 256 threads = 4 waves. global_load_lds staging.
// EPI: 0 = bias, bf16 out              (QKV)
//      5 = bf16 out, col<Nvalid guard  (WcT)
//      6 = unsafeAtomicAdd f32, no scale (FFN2' split-K)
// ---------------------------------------------------------------------------
template<int EPI>
__global__ __launch_bounds__(256)
void gemm_bt(const bf16* __restrict__ Abase, const bf16* __restrict__ Bbase,
             void* __restrict__ Cbase, const float* __restrict__ biasBase,
             int K, int lda, int ldb, int ldc, int Nvalid,
             int zb0, int zdiv,
             long sAq, long sAr, long sAz,
             long sBq, long sBr, long sBz,
             long sCq, long sCr, long sCz,
             long sBiasq)
{
    int bz = blockIdx.z;
    int za = zb0 + bz;
    int zq = za / zdiv, zr = za - zq*zdiv;
    const bf16* A = Abase + (long)zq*sAq + (long)zr*sAr + (long)bz*sAz;
    const bf16* B = Bbase + (long)zq*sBq + (long)zr*sBr + (long)bz*sBz;
    const float* bias = biasBase ? (biasBase + (long)zq*sBiasq) : nullptr;
    long coff = (long)zq*sCq + (long)zr*sCr + (long)bz*sCz;

    __shared__ bf16 As[128*32];
    __shared__ bf16 Bs[128*32];

    int nwg  = gridDim.x * gridDim.y;
    int orig = blockIdx.y * gridDim.x + blockIdx.x;
    int q8 = nwg >> 3, r8 = nwg & 7;
    int xcd = orig & 7, idx = orig >> 3;
    int wg = (xcd < r8 ? xcd*(q8+1) : r8*(q8+1) + (xcd-r8)*q8) + idx;
    int bn = wg % gridDim.x, bm = wg / gridDim.x;

    int t = threadIdx.x;
    int wave = t >> 6, lane = t & 63;
    int wm = (wave >> 1) << 6;   // 0 or 64
    int wn = (wave & 1) << 6;
    int lr = lane & 15, lg = lane >> 4;

    f32x4 acc[4][4] = {};

    int arow = t >> 2;              // 0..63
    int acol = (t & 3) << 3;        // 0,8,16,24
    const bf16* Ag0 = A + (long)(bm*128 + arow)*lda + acol;
    const bf16* Ag1 = Ag0 + (long)64*lda;
    const bf16* Bg0 = B + (long)(bn*128 + arow)*ldb + acol;
    const bf16* Bg1 = Bg0 + (long)64*ldb;
    bf16* Al = As + t*8;
    bf16* Bl = Bs + t*8;

    for (int k0 = 0; k0 < K; k0 += 32) {
        __syncthreads();
        gload16(Ag0, Al);
        gload16(Ag1, Al + 64*32);
        gload16(Bg0, Bl);
        gload16(Bg1, Bl + 64*32);
        Ag0 += 32; Ag1 += 32; Bg0 += 32; Bg1 += 32;
        __syncthreads();
        short8 af[4], bfr[4];
        #pragma unroll
        for (int m=0;m<4;m++) af[m]  = *(short8*)&As[(wm + m*16 + lr)*32 + lg*8];
        #pragma unroll
        for (int n=0;n<4;n++) bfr[n] = *(short8*)&Bs[(wn + n*16 + lr)*32 + lg*8];
        #pragma unroll
        for (int m=0;m<4;m++)
            #pragma unroll
            for (int n=0;n<4;n++)
                acc[m][n] = __builtin_amdgcn_mfma_f32_16x16x32_bf16(af[m], bfr[n], acc[m][n], 0,0,0);
    }

    #pragma unroll
    for (int m=0;m<4;m++){
        #pragma unroll
        for (int n=0;n<4;n++){
            int col = bn*128 + wn + n*16 + lr;
            float bcol = 0.f;
            if constexpr (EPI==0) bcol = bias[col];
            #pragma unroll
            for (int i=0;i<4;i++){
                long row = (long)bm*128 + wm + m*16 + lg*4 + i;
                float v = acc[m][n][i];
                if constexpr (EPI==0){
                    ((bf16*)Cbase + coff)[row*ldc+col] = f2bf(v + bcol);
                } else if constexpr (EPI==5){
                    if (col < Nvalid) ((bf16*)Cbase + coff)[row*ldc+col] = f2bf(v);
                } else {
                    unsafeAtomicAdd((float*)Cbase + coff + row*ldc + col, v);
                }
            }
        }
    }
}

// ---------------------------------------------------------------------------
// Fused flash attention (max-free single pass; scores provably small).
// One block = (b,h) x 64 q-rows; 4 waves x 16 q-rows. Zero barriers:
// per-wave LDS scratch for P (XOR-granule swizzle), per-wave DS ordering.
// O = sum_kt exp(s*0.125+mask) @ V ; out = O / l.
// ---------------------------------------------------------------------------
__global__ __launch_bounds__(256)
void flash_attn(const bf16* __restrict__ qkv, const bf16* __restrict__ Vt,
                const float* __restrict__ mask, bf16* __restrict__ ctx2)
{
    __shared__ __align__(16) char p_lds[8192];   // 4 waves x [16 q][64 k] bf16
    int z = blockIdx.y;
    int b = z / NH, h = z - b*NH;
    int qb = blockIdx.x * 64;
    int t = threadIdx.x;
    int wave = t >> 6, lane = t & 63;
    int lr = lane & 15, lg = lane >> 4;
    int x7 = lr & 7;
    int gb0 = ((lg    ) ^ x7) << 4;
    int gb1 = ((4 | lg) ^ x7) << 4;

    // Q A-frags direct from global (row = wave*16+lr, k-slices of d)
    const bf16* Qp = qkv + (long)(b*SEQ + qb + wave*16 + lr)*(3*HIDN) + h*HD + lg*8;
    short8 aq0 = *(const short8*)(Qp);
    short8 aq1 = *(const short8*)(Qp + 32);

    const bf16* Kb = qkv + (long)b*SEQ*(3*HIDN) + HIDN + h*HD + lg*8;
    const bf16* Vb = Vt + (long)z*HD*SEQ;
    const float* mb = mask + b*SEQ;
    char* pw = p_lds + wave*2048;

    f32x4 o[4] = {};
    float lsum[4] = {0.f,0.f,0.f,0.f};

    for (int kt = 0; kt < 8; ++kt){
        int kbase = kt*64;
        // K B-frags (K is naturally [s][d] K-major for QK^T)
        short8 bk0[4], bk1[4];
        #pragma unroll
        for (int nf=0;nf<4;nf++){
            const bf16* kp = Kb + (long)(kbase + nf*16 + lr)*(3*HIDN);
            bk0[nf] = *(const short8*)(kp);
            bk1[nf] = *(const short8*)(kp + 32);
        }
        f32x4 s[4] = {};
        #pragma unroll
        for (int nf=0;nf<4;nf++){
            s[nf] = __builtin_amdgcn_mfma_f32_16x16x32_bf16(aq0, bk0[nf], s[nf], 0,0,0);
            s[nf] = __builtin_amdgcn_mfma_f32_16x16x32_bf16(aq1, bk1[nf], s[nf], 0,0,0);
        }
        // V B-frags from Vt [d][s]
        short8 bv0[4], bv1[4];
        #pragma unroll
        for (int nf=0;nf<4;nf++){
            const bf16* vp = Vb + (long)(nf*16 + lr)*SEQ + kbase + lg*8;
            bv0[nf] = *(const short8*)(vp);
            bv1[nf] = *(const short8*)(vp + 32);
        }
        // exp (no max-sub) + row-partial l + P -> LDS (C-layout write, swizzled)
        #pragma unroll
        for (int nf=0;nf<4;nf++){
            float mk = mb[kbase + nf*16 + lr];
            int gk = nf*2 + (lr>>3);
            #pragma unroll
            for (int i=0;i<4;i++){
                int q = lg*4 + i;
                float e = __expf(fmaf(s[nf][i], 0.125f, mk));
                lsum[i] += e;
                *(bf16*)(pw + q*128 + ((gk ^ (q&7))<<4) + (lr&7)*2) = f2bf(e);
            }
        }
        // PV: read P as A-frags (row=lr, swizzled granules)
        short8 ap0 = *(const short8*)(pw + lr*128 + gb0);
        short8 ap1 = *(const short8*)(pw + lr*128 + gb1);
        #pragma unroll
        for (int nf=0;nf<4;nf++){
            o[nf] = __builtin_amdgcn_mfma_f32_16x16x32_bf16(ap0, bv0[nf], o[nf], 0,0,0);
            o[nf] = __builtin_amdgcn_mfma_f32_16x16x32_bf16(ap1, bv1[nf], o[nf], 0,0,0);
        }
    }
    #pragma unroll
    for (int i=0;i<4;i++){
        float v = lsum[i];
        v += __shfl_xor(v, 1, 64);
        v += __shfl_xor(v, 2, 64);
        v += __shfl_xor(v, 4, 64);
        v += __shfl_xor(v, 8, 64);
        lsum[i] = __builtin_amdgcn_rcpf(v);
    }
    bf16* Cp = ctx2 + (long)(b*SEQ + qb + wave*16)*HIDN + h*HD;
    #pragma unroll
    for (int nf=0;nf<4;nf++)
        #pragma unroll
        for (int i=0;i<4;i++)
            Cp[(long)(lg*4+i)*HIDN + nf*16 + lr] = f2bf(o[nf][i] * lsum[i]);
}

// ---------------------------------------------------------------------------
// Fused per-head FFN1 + head reduction (v3: 128x64 tile, 768 blocks):
// S[t][i] = sum_h w_a[h]*gelu( w_kp[h]*(ctx2[t]@WcT[i])_h + bhc[h][i] )
// 512 thr = 8 waves (4M x 2N), per head BK=64 single stage, XOR swizzle,
// prev head's gelu-merge placed between load-issue and barrier.
// ---------------------------------------------------------------------------
__global__ __launch_bounds__(512)
void gemm_heads(const bf16* __restrict__ A, const bf16* __restrict__ B,
                bf16* __restrict__ S, const float* __restrict__ bhc,
                const float* __restrict__ w_kp, const float* __restrict__ w_a)
{
    __shared__ __align__(16) char hlds[24576];   // A 16KB @0, B 8KB @16384

    int nwg  = gridDim.x * gridDim.y;
    int orig = blockIdx.y * gridDim.x + blockIdx.x;
    int q8 = nwg >> 3, r8 = nwg & 7;
    int xcd = orig & 7, idx = orig >> 3;
    int wg = (xcd < r8 ? xcd*(q8+1) : r8*(q8+1) + (xcd-r8)*q8) + idx;
    int bn = wg % gridDim.x, bm = wg / gridDim.x;

    int t = threadIdx.x;
    int wave = t >> 6, lane = t & 63;
    int wm = (wave >> 1) << 5;    // 0,32,64,96
    int wn = (wave & 1) << 5;     // 0,32
    int lr = lane & 15, lg = lane >> 4;
    int x7 = lr & 7;
    int gb0 = ((lg    ) ^ x7) << 4;
    int gb1 = ((4 | lg) ^ x7) << 4;

    int srow = t >> 3;
    int glog = (t & 7) ^ (srow & 7);
    const bf16* Ag0 = A + (long)(bm*128 + srow)*HIDN + glog*8;
    const bf16* Ag1 = Ag0 + (long)64*HIDN;
    const bf16* Bg0 = B + (long)(bn*64 + srow)*HIDN + glog*8;

    f32x4 acc[2][2] = {};
    f32x4 sacc[2][2] = {};
    int cols[2];
    #pragma unroll
    for (int n=0;n<2;n++) cols[n] = bn*64 + wn + n*16 + lr;

    for (int h = 0; h < NH; ++h){
        __syncthreads();                       // prev iter's ds_reads done
        gload16(Ag0, (bf16*)(hlds + t*16));
        gload16(Ag1, (bf16*)(hlds + 8192  + t*16));
        gload16(Bg0, (bf16*)(hlds + 16384 + t*16));
        Ag0 += 64; Ag1 += 64; Bg0 += 64;

        if (h > 0){                            // gelu-merge head h-1 hides latency
            float wk = w_kp[h-1], wa = w_a[h-1];
            float bh[2];
            #pragma unroll
            for (int n=0;n<2;n++) bh[n] = bhc[(h-1)*ISZ + cols[n]];
            #pragma unroll
            for (int m=0;m<2;m++)
                #pragma unroll
                for (int n=0;n<2;n++)
                    #pragma unroll
                    for (int i=0;i<4;i++){
                        float v = fmaf(wk, acc[m][n][i], bh[n]);
                        sacc[m][n][i] += wa * gelu_fast(v);
                        acc[m][n][i] = 0.f;
                    }
        }
        __syncthreads();                       // drains vmcnt -> LDS ready

        short8 af[2][2], bfr[2][2];
        #pragma unroll
        for (int m=0;m<2;m++){
            const char* pr = hlds + (wm + m*16 + lr)*128;
            af[m][0] = *(const short8*)(pr + gb0);
            af[m][1] = *(const short8*)(pr + gb1);
        }
        #pragma unroll
        for (int n=0;n<2;n++){
            const char* pr = hlds + 16384 + (wn + n*16 + lr)*128;
            bfr[n][0] = *(const short8*)(pr + gb0);
            bfr[n][1] = *(const short8*)(pr + gb1);
        }
        #pragma unroll
        for (int m=0;m<2;m++)
            #pragma unroll
            for (int n=0;n<2;n++)
                #pragma unroll
                for (int kk=0;kk<2;kk++)
                    acc[m][n] = __builtin_amdgcn_mfma_f32_16x16x32_bf16(af[m][kk], bfr[n][kk], acc[m][n], 0,0,0);
    }

    {   // final head
        float wk = w_kp[NH-1], wa = w_a[NH-1];
        float bh[2];
        #pragma unroll
        for (int n=0;n<2;n++) bh[n] = bhc[(NH-1)*ISZ + cols[n]];
        #pragma unroll
        for (int m=0;m<2;m++)
            #pragma unroll
            for (int n=0;n<2;n++)
                #pragma unroll
                for (int i=0;i<4;i++){
                    float v = fmaf(wk, acc[m][n][i], bh[n]);
                    sacc[m][n][i] += wa * gelu_fast(v);
                }
    }

    #pragma unroll
    for (int m=0;m<2;m++)
        #pragma unroll
        for (int n=0;n<2;n++)
            #pragma unroll
            for (int i=0;i<4;i++){
                long row = (long)bm*128 + wm + m*16 + lg*4 + i;
                S[row*ISZ + cols[n]] = f2bf(sacc[m][n][i]);
            }
}

// bhc[h][i] = w_kp[h]*(bo_h @ Wi)[i] + bi[i]
__global__ void bhc_kernel(const float* __restrict__ bo, const float* __restrict__ Wi,
                           const float* __restrict__ bi, const float* __restrict__ w_kp,
                           float* __restrict__ bhc)
{
    int i = blockIdx.x*256 + threadIdx.x;
    if (i >= NH*ISZ) return;
    int h = i / ISZ, c = i - h*ISZ;
    float s = 0.f;
    for (int m = 0; m < HIDN; ++m) s += bo[h*HIDN + m] * Wi[(long)m*ISZ + c];
    bhc[i] = w_kp[h]*s + bi[c];
}

// ---------------------------------------------------------------------------
__global__ __launch_bounds__(256)
void transpose_cvt(const float* __restrict__ src, bf16* __restrict__ dst,
                   int R, int C, long sSrcZ, long sDstZ)
{
    __shared__ float tile[32][33];
    src += (long)blockIdx.z * sSrcZ;
    dst += (long)blockIdx.z * sDstZ;
    int c0 = blockIdx.x*32, r0 = blockIdx.y*32;
    int tx = threadIdx.x & 31, ty = threadIdx.x >> 5;
    #pragma unroll
    for (int i=0;i<32;i+=8) tile[ty+i][tx] = src[(long)(r0+ty+i)*C + c0+tx];
    __syncthreads();
    #pragma unroll
    for (int i=0;i<32;i+=8) dst[(long)(c0+ty+i)*R + r0+tx] = f2bf(tile[tx][ty+i]);
}

// bf16 V transpose: per z=(b,h): qkv V-slice [512 s][64 d] -> Vt[z][64 d][512 s]
__global__ __launch_bounds__(256)
void transpose_v(const bf16* __restrict__ qkv, bf16* __restrict__ Vt)
{
    __shared__ bf16 tile[32][33];
    int za = blockIdx.z; int b = za/NH, h = za - b*NH;
    const bf16* src = qkv + (long)b*SEQ*3*HIDN + 2*HIDN + h*HD;
    bf16* dst = Vt + (long)za*HD*SEQ;
    int d0 = blockIdx.x*32, s0 = blockIdx.y*32;
    int tx = threadIdx.x & 31, ty = threadIdx.x >> 5;
    #pragma unroll
    for (int i=0;i<32;i+=8) tile[ty+i][tx] = src[(long)(s0+ty+i)*(3*HIDN) + d0+tx];
    __syncthreads();
    #pragma unroll
    for (int i=0;i<32;i+=8) dst[(long)(d0+ty+i)*SEQ + s0+tx] = tile[tx][ty+i];
}

__global__ void cvt_bf16(const float* __restrict__ in, bf16* __restrict__ out, int n){
    int i = blockIdx.x*blockDim.x + threadIdx.x;
    if (i < n) out[i] = f2bf(in[i]);
}

__global__ void concat_bias(const float* __restrict__ bq, const float* __restrict__ bk,
                            const float* __restrict__ bv, float* __restrict__ bqkv){
    int i = blockIdx.x*blockDim.x + threadIdx.x;
    if (i < 3*HIDN) bqkv[i] = (i < HIDN) ? bq[i] : (i < 2*HIDN ? bk[i-HIDN] : bv[i-2*HIDN]);
}

__global__ __launch_bounds__(256)
void add_ln(const float* __restrict__ hidden, const float* __restrict__ out_acc,
            const float* __restrict__ bout, const float* __restrict__ w_a,
            const float* __restrict__ gamma, const float* __restrict__ beta,
            float* __restrict__ out)
{
    __shared__ float red[8];
    int row = blockIdx.x;
    int t = threadIdx.x;
    int wave = t>>6, lane = t&63;
    float swa = 0.f;
    #pragma unroll
    for (int h=0;h<NH;h++) swa += w_a[h];
    float x[3];
    float sum = 0.f;
    #pragma unroll
    for (int j=0;j<3;j++){
        int c = j*256 + t;
        x[j] = hidden[(long)row*HIDN + c] + out_acc[(long)row*HIDN + c] + swa*bout[c];
        sum += x[j];
    }
    #pragma unroll
    for (int o=32;o>0;o>>=1) sum += __shfl_xor(sum,o,64);
    if (lane==0) red[wave]=sum;
    __syncthreads();
    sum = red[0]+red[1]+red[2]+red[3];
    float u = sum * (1.0f/768.0f);
    float vs = 0.f;
    #pragma unroll
    for (int j=0;j<3;j++){ float d = x[j]-u; vs += d*d; }
    #pragma unroll
    for (int o=32;o>0;o>>=1) vs += __shfl_xor(vs,o,64);
    __syncthreads();
    if (lane==0) red[4+wave]=vs;
    __syncthreads();
    vs = red[4]+red[5]+red[6]+red[7];
    float rstd = rsqrtf(vs*(1.0f/768.0f) + 1e-12f);
    #pragma unroll
    for (int j=0;j<3;j++){
        int c = j*256 + t;
        out[(long)row*HIDN + c] = gamma[c]*(x[j]-u)*rstd + beta[c];
    }
}

extern "C" void kernel_launch(void* const* d_in, const int* in_sizes, int n_in,
                              void* d_out, int out_size, void* d_ws, size_t ws_size,
                              hipStream_t stream)
{
    const float* hidden = (const float*)d_in[0];
    const float* mask   = (const float*)d_in[1];
    const float* Wq = (const float*)d_in[2];
    const float* bq = (const float*)d_in[3];
    const float* Wk = (const float*)d_in[4];
    const float* bk = (const float*)d_in[5];
    const float* Wv = (const float*)d_in[6];
    const float* bv = (const float*)d_in[7];
    const float* Wo = (const float*)d_in[8];
    const float* bo = (const float*)d_in[9];
    const float* w_kp = (const float*)d_in[10];
    const float* w_a  = (const float*)d_in[11];
    const float* Wi = (const float*)d_in[12];
    const float* bi = (const float*)d_in[13];
    const float* Wout = (const float*)d_in[14];
    const float* boutp = (const float*)d_in[15];
    const float* gamma = (const float*)d_in[16];
    const float* beta  = (const float*)d_in[17];
    float* out = (float*)d_out;

    char* w = (char*)d_ws;
    auto alloc = [&](size_t bytes)->char* {
        char* p = w; w += (bytes + 255) & ~(size_t)255; return p;
    };
    bf16*  hbf    = (bf16*) alloc((size_t)NTOK*HIDN*2);
    bf16*  WqkvT  = (bf16*) alloc((size_t)3*HIDN*HIDN*2);
    float* bqkv   = (float*)alloc((size_t)3*HIDN*4);
    bf16*  WiT    = (bf16*) alloc((size_t)ISZ*HIDN*2);
    bf16*  WoutT  = (bf16*) alloc((size_t)HIDN*ISZ*2);
    bf16*  Wobf   = (bf16*) alloc((size_t)HIDN*HIDN*2);     // Wo stacked [768][768]
    bf16*  WcT    = (bf16*) alloc((size_t)ISZ*HIDN*2);      // (Wo@Wi)^T  [3072][768]
    float* bhc    = (float*)alloc((size_t)NH*ISZ*4);        // [12][3072]
    bf16*  qkv    = (bf16*) alloc((size_t)NTOK*3*HIDN*2);
    bf16*  ctx2   = (bf16*) alloc((size_t)NTOK*HIDN*2);     // [2048][h*64+d]
    bf16*  Sbuf   = (bf16*) alloc((size_t)NTOK*ISZ*2);      // [2048][3072]
    float* out_acc= (float*)alloc((size_t)NTOK*HIDN*4);
    bf16*  Vt     = (bf16*) alloc((size_t)NH*4*HD*SEQ*2);   // [48][64][512]

    // ---- prep: convert / transpose weights ----
    cvt_bf16<<<(NTOK*HIDN+255)/256, 256, 0, stream>>>(hidden, hbf, NTOK*HIDN);
    cvt_bf16<<<(HIDN*HIDN+255)/256, 256, 0, stream>>>(Wo, Wobf, HIDN*HIDN);
    concat_bias<<<(3*HIDN+255)/256, 256, 0, stream>>>(bq, bk, bv, bqkv);
    transpose_cvt<<<dim3(HIDN/32, HIDN/32, 1), 256, 0, stream>>>(Wq, WqkvT,              HIDN, HIDN, 0, 0);
    transpose_cvt<<<dim3(HIDN/32, HIDN/32, 1), 256, 0, stream>>>(Wk, WqkvT + HIDN*HIDN,  HIDN, HIDN, 0, 0);
    transpose_cvt<<<dim3(HIDN/32, HIDN/32, 1), 256, 0, stream>>>(Wv, WqkvT + 2*HIDN*HIDN,HIDN, HIDN, 0, 0);
    transpose_cvt<<<dim3(ISZ/32,  HIDN/32, 1), 256, 0, stream>>>(Wi,   WiT,   HIDN, ISZ, 0, 0);
    transpose_cvt<<<dim3(HIDN/32, ISZ/32,  1), 256, 0, stream>>>(Wout, WoutT, ISZ, HIDN, 0, 0);
    bhc_kernel<<<(NH*ISZ+255)/256, 256, 0, stream>>>(bo, Wi, bi, w_kp, bhc);

    // WcT[i][hd] = sum_m Wi[m][i]*Wo[hd][m]
    gemm_bt<5><<<dim3(HIDN/128, ISZ/128, 1), 256, 0, stream>>>(
        WiT, Wobf, WcT, nullptr,
        HIDN, HIDN, HIDN, HIDN, HIDN,
        0, 1,
        0,0,0, 0,0,0, 0,0,0, 0);

    // ---- QKV projection: [2048,768] @ [2304,768]^T ----
    gemm_bt<0><<<dim3(3*HIDN/128, NTOK/128, 1), 256, 0, stream>>>(
        hbf, WqkvT, qkv, bqkv,
        HIDN, HIDN, HIDN, 3*HIDN, 3*HIDN,
        0, 1,
        0,0,0, 0,0,0, 0,0,0, 0);

    // ---- attention: V transpose + fused flash (scores/softmax/PV in one) ----
    transpose_v<<<dim3(2,16,48), 256, 0, stream>>>(qkv, Vt);
    flash_attn<<<dim3(SEQ/64, 48), 256, 0, stream>>>(qkv, Vt, mask, ctx2);

    // ---- fused per-head FFN1 + head-reduce -> S ----
    gemm_heads<<<dim3(ISZ/64, NTOK/128, 1), 512, 0, stream>>>(
        ctx2, WcT, Sbuf, bhc, w_kp, w_a);

    // ---- FFN2': out_acc = S @ WoutT^T  (split-K=4, atomic f32) ----
    hipMemsetAsync(out_acc, 0, (size_t)NTOK*HIDN*4, stream);
    gemm_bt<6><<<dim3(HIDN/128, NTOK/128, 4), 256, 0, stream>>>(
        Sbuf, WoutT, out_acc, nullptr,
        ISZ/4, ISZ, ISZ, HIDN, HIDN,
        0, 1,
        (long)(ISZ/4), 0, 0,
        (long)(ISZ/4), 0, 0,
        0, 0, 0,
        0);

    // ---- residual + sum(w_a)*bout + LayerNorm ----
    add_ln<<<NTOK, 256, 0, stream>>>(hidden, out_acc, boutp, w_a, gamma, beta, out);
}